// Round 2
// baseline (1992.144 us; speedup 1.0000x reference)
//
#include <hip/hip_runtime.h>
#include <math.h>

#define N_NODES 50000
#define N_EDGES 800000
#define N_GRAPHS 500
#define DIM 64
#define RBF_DIM 5
#define N_CONV 3
#define CLS_DIM 2000
#define ACT_DIM 100
#define HID 256

// _sp2(x) = 2 * softplus(0.5x), numerically stable
__device__ __forceinline__ float sp2f(float x){
    float y = 0.5f * x;
    return 2.0f * (fmaxf(y, 0.0f) + log1pf(__expf(-fabsf(y))));
}
// ShiftSoftplus: softplus(x) - ln(2)
__device__ __forceinline__ float sspf(float x){
    return fmaxf(x, 0.0f) + log1pf(__expf(-fabsf(x))) - 0.69314718055994531f;
}

__global__ void k_embed(const int* __restrict__ types, const float* __restrict__ emb,
                        float* __restrict__ node){
    int i = blockIdx.x * 256 + threadIdx.x;
    if (i < N_NODES * DIM) node[i] = emb[types[i >> 6] * DIM + (i & 63)];
}

__global__ void k_counts(const int* __restrict__ gid, float* __restrict__ counts){
    int i = blockIdx.x * 256 + threadIdx.x;
    if (i < N_NODES) atomicAdd(&counts[gid[i]], 1.0f);
}

// out[n] = in[n] @ W   (64x64, W in LDS). 256 thr = 4 rows x 64 cols, 16 rows/block.
__global__ __launch_bounds__(256) void k_gemm64(const float* __restrict__ in,
                                                const float* __restrict__ W,
                                                float* __restrict__ out){
    __shared__ float sW[64 * 64];
    __shared__ float sIn[4 * 64];
    int tid = threadIdx.x;
    int c = tid & 63, r = tid >> 6;
    for (int i = tid; i < 64 * 64; i += 256) sW[i] = W[i];
    __syncthreads();
    int base = blockIdx.x * 16;
    for (int it = 0; it < 4; ++it){
        int n = base + it * 4 + r;
        bool ok = (n < N_NODES);
        if (ok) sIn[r * 64 + c] = in[n * 64 + c];
        __syncthreads();
        if (ok){
            float acc = 0.f;
            #pragma unroll 8
            for (int k = 0; k < 64; ++k) acc += sIn[r * 64 + k] * sW[k * 64 + c];
            out[n * 64 + c] = acc;
        }
        __syncthreads();
    }
}

// Fused edge conv: rbf -> sp2(rbf@cf1+b) -> sp2(h1@cf2+b) -> gather*filter -> scatter-add
// 256 thr = 4 edge-groups x 64 chans; 64 edges per block.
__global__ __launch_bounds__(256) void k_edge(const float* __restrict__ dist,
    const int* __restrict__ esrc, const int* __restrict__ edst,
    const float* __restrict__ cf1w, const float* __restrict__ cf1b,
    const float* __restrict__ cf2w, const float* __restrict__ cf2b,
    const float* __restrict__ new_node, float* __restrict__ agg)
{
    __shared__ float s_cf1[RBF_DIM * 64];
    __shared__ float s_cf1b[64];
    __shared__ float s_cf2[64 * 64];
    __shared__ float s_cf2b[64];
    __shared__ float s_h1[4 * 64];
    int tid = threadIdx.x;
    int c = tid & 63, g = tid >> 6;
    for (int i = tid; i < 64 * 64; i += 256) s_cf2[i] = cf2w[i];
    // FIX R1: RBF_DIM*64 = 320 > blockDim (256) — must stride, else row j=4
    // (center 5.0) of cf1_w is uninitialized LDS garbage.
    for (int i = tid; i < RBF_DIM * 64; i += 256) s_cf1[i] = cf1w[i];
    if (tid < 64){ s_cf1b[tid] = cf1b[tid]; s_cf2b[tid] = cf2b[tid]; }
    __syncthreads();
    int base = blockIdx.x * 64;
    for (int it = 0; it < 16; ++it){
        int e = base + it * 4 + g;
        bool ok = (e < N_EDGES);
        if (ok){
            float d = dist[e];
            float acc = s_cf1b[c];
            #pragma unroll
            for (int j = 0; j < RBF_DIM; ++j){
                float t = d - 1.25f * (float)j;          // centers = linspace(0,5,5)
                acc += __expf(-0.8f * t * t) * s_cf1[j * 64 + c];  // 1/gap = 0.8
            }
            s_h1[g * 64 + c] = sp2f(acc);
        }
        __syncthreads();
        if (ok){
            float acc = s_cf2b[c];
            #pragma unroll 8
            for (int k = 0; k < 64; ++k) acc += s_h1[g * 64 + k] * s_cf2[k * 64 + c];
            float eh = sp2f(acc);
            int s = esrc[e], dd = edst[e];
            atomicAdd(&agg[dd * 64 + c], new_node[s * 64 + c] * eh);
        }
        __syncthreads();
    }
}

// node += sp2(agg@nl2 + b2) @ nl3 + b3
__global__ __launch_bounds__(256) void k_update(const float* __restrict__ agg,
    const float* __restrict__ nl2w, const float* __restrict__ nl2b,
    const float* __restrict__ nl3w, const float* __restrict__ nl3b,
    float* __restrict__ node)
{
    __shared__ float s_w2[64 * 64], s_w3[64 * 64];
    __shared__ float s_b2[64], s_b3[64];
    __shared__ float s_in[4 * 64], s_t[4 * 64];
    int tid = threadIdx.x;
    int c = tid & 63, r = tid >> 6;
    for (int i = tid; i < 4096; i += 256){ s_w2[i] = nl2w[i]; s_w3[i] = nl3w[i]; }
    if (tid < 64){ s_b2[tid] = nl2b[tid]; s_b3[tid] = nl3b[tid]; }
    __syncthreads();
    int base = blockIdx.x * 16;
    for (int it = 0; it < 4; ++it){
        int n = base + it * 4 + r;
        bool ok = (n < N_NODES);
        if (ok) s_in[r * 64 + c] = agg[n * 64 + c];
        __syncthreads();
        if (ok){
            float acc = s_b2[c];
            #pragma unroll 8
            for (int k = 0; k < 64; ++k) acc += s_in[r * 64 + k] * s_w2[k * 64 + c];
            s_t[r * 64 + c] = sp2f(acc);
        }
        __syncthreads();
        if (ok){
            float acc = s_b3[c];
            #pragma unroll 8
            for (int k = 0; k < 64; ++k) acc += s_t[r * 64 + k] * s_w3[k * 64 + c];
            node[n * 64 + c] += acc;
        }
        __syncthreads();
    }
}

// Fused readout per 8 nodes: atom=ssp(node@d1+b); res=atom@d2+b;
// graph-pool atomicAdd(res); atoms_preds = relu(res)@ac + b.
__global__ __launch_bounds__(256) void k_readout(const float* __restrict__ node,
    const float* __restrict__ d1w, const float* __restrict__ d1b,
    const float* __restrict__ d2w, const float* __restrict__ d2b,
    const float* __restrict__ acw, const float* __restrict__ acb,
    const int* __restrict__ gid,
    float* __restrict__ gacc, float* __restrict__ out_atoms)
{
    __shared__ float s_node[8 * 64];
    __shared__ float s_atom[8 * 256];
    __shared__ float s_res[8 * 256];
    int tid = threadIdx.x;
    int base = blockIdx.x * 8;
    for (int i = tid; i < 8 * 64; i += 256){
        int n = base + (i >> 6);
        s_node[i] = (n < N_NODES) ? node[n * 64 + (i & 63)] : 0.f;
    }
    __syncthreads();
    { // stage 1: atom rows (col = tid)
        float acc[8];
        #pragma unroll
        for (int r = 0; r < 8; ++r) acc[r] = 0.f;
        for (int k = 0; k < 64; ++k){
            float w = d1w[k * 256 + tid];
            #pragma unroll
            for (int r = 0; r < 8; ++r) acc[r] += s_node[r * 64 + k] * w;
        }
        float b = d1b[tid];
        #pragma unroll
        for (int r = 0; r < 8; ++r) s_atom[r * 256 + tid] = sspf(acc[r] + b);
    }
    __syncthreads();
    { // stage 2: res rows + graph pool
        float acc[8];
        #pragma unroll
        for (int r = 0; r < 8; ++r) acc[r] = 0.f;
        for (int k = 0; k < 256; ++k){
            float w = d2w[k * 256 + tid];
            #pragma unroll
            for (int r = 0; r < 8; ++r) acc[r] += s_atom[r * 256 + k] * w;
        }
        float b = d2b[tid];
        #pragma unroll
        for (int r = 0; r < 8; ++r){
            int n = base + r;
            float v = acc[r] + b;
            s_res[r * 256 + tid] = fmaxf(v, 0.f);
            if (n < N_NODES) atomicAdd(&gacc[gid[n] * 256 + tid], v);
        }
    }
    __syncthreads();
    // stage 3: atoms_preds (8 rows x 100 cols as a task loop)
    for (int task = tid; task < 8 * ACT_DIM; task += 256){
        int r = task / ACT_DIM, j = task - r * ACT_DIM;
        int n = base + r;
        if (n >= N_NODES) continue;
        float acc = acb[j];
        for (int k = 0; k < 256; ++k) acc += s_res[r * 256 + k] * acw[k * ACT_DIM + j];
        out_atoms[n * ACT_DIM + j] = acc;
    }
}

__global__ __launch_bounds__(256) void k_cls(const float* __restrict__ gacc,
    const float* __restrict__ counts, const float* __restrict__ clsw,
    const float* __restrict__ clsb, float* __restrict__ out_cls)
{
    __shared__ float s_e[256];
    int g = blockIdx.x, tid = threadIdx.x;
    float cnt = fmaxf(counts[g], 1.0f);
    s_e[tid] = gacc[g * 256 + tid] / cnt;
    __syncthreads();
    for (int j = tid; j < CLS_DIM; j += 256){
        float acc = clsb[j];
        for (int k = 0; k < 256; ++k) acc += s_e[k] * clsw[k * CLS_DIM + j];
        out_cls[g * CLS_DIM + j] = acc;
    }
}

extern "C" void kernel_launch(void* const* d_in, const int* in_sizes, int n_in,
                              void* d_out, int out_size, void* d_ws, size_t ws_size,
                              hipStream_t stream)
{
    const int*   node_types = (const int*)d_in[0];
    const int*   edge_src   = (const int*)d_in[1];
    const int*   edge_dst   = (const int*)d_in[2];
    const int*   graph_ids  = (const int*)d_in[3];
    const float* distance   = (const float*)d_in[4];
    const float* emb        = (const float*)d_in[5];
    const float* conv_w1    = (const float*)d_in[6];
    const float* cf1_w      = (const float*)d_in[7];
    const float* cf1_b      = (const float*)d_in[8];
    const float* cf2_w      = (const float*)d_in[9];
    const float* cf2_b      = (const float*)d_in[10];
    const float* nl2_w      = (const float*)d_in[11];
    const float* nl2_b      = (const float*)d_in[12];
    const float* nl3_w      = (const float*)d_in[13];
    const float* nl3_b      = (const float*)d_in[14];
    const float* d1_w       = (const float*)d_in[15];
    const float* d1_b       = (const float*)d_in[16];
    const float* d2_w       = (const float*)d_in[17];
    const float* d2_b       = (const float*)d_in[18];
    const float* cls_w      = (const float*)d_in[19];
    const float* cls_b      = (const float*)d_in[20];
    const float* ac_w       = (const float*)d_in[21];
    const float* ac_b       = (const float*)d_in[22];

    float* ws       = (float*)d_ws;
    float* node     = ws;                        // N*64
    float* new_node = node + N_NODES * DIM;      // N*64
    float* agg      = new_node + N_NODES * DIM;  // N*64
    float* gacc     = agg + N_NODES * DIM;       // 500*256
    float* counts   = gacc + N_GRAPHS * HID;     // 500
    float* out      = (float*)d_out;

    hipMemsetAsync(gacc, 0, (N_GRAPHS * HID + N_GRAPHS) * sizeof(float), stream);
    k_embed<<<(N_NODES * DIM + 255) / 256, 256, 0, stream>>>(node_types, emb, node);
    k_counts<<<(N_NODES + 255) / 256, 256, 0, stream>>>(graph_ids, counts);

    for (int i = 0; i < N_CONV; ++i){
        k_gemm64<<<(N_NODES + 15) / 16, 256, 0, stream>>>(node, conv_w1 + i * DIM * DIM, new_node);
        hipMemsetAsync(agg, 0, N_NODES * DIM * sizeof(float), stream);
        k_edge<<<(N_EDGES + 63) / 64, 256, 0, stream>>>(distance, edge_src, edge_dst,
            cf1_w + i * RBF_DIM * DIM, cf1_b + i * DIM,
            cf2_w + i * DIM * DIM, cf2_b + i * DIM, new_node, agg);
        k_update<<<(N_NODES + 15) / 16, 256, 0, stream>>>(agg,
            nl2_w + i * DIM * DIM, nl2_b + i * DIM,
            nl3_w + i * DIM * DIM, nl3_b + i * DIM, node);
    }

    k_readout<<<(N_NODES + 7) / 8, 256, 0, stream>>>(node, d1_w, d1_b, d2_w, d2_b,
        ac_w, ac_b, graph_ids, gacc, out);
    k_cls<<<N_GRAPHS, 256, 0, stream>>>(gacc, counts, cls_w, cls_b, out + N_NODES * ACT_DIM);
}

// Round 3
// 1233.973 us; speedup vs baseline: 1.6144x; 1.6144x over previous
//
#include <hip/hip_runtime.h>
#include <math.h>

#define N_NODES 50000
#define N_EDGES 800000
#define N_GRAPHS 500
#define DIM 64
#define RBF_DIM 5
#define N_CONV 3
#define CLS_DIM 2000
#define ACT_DIM 100
#define HID 256
#define TAB 2048          // filter lookup-table entries over d in [0,5]

// _sp2(x) = 2 * softplus(0.5x), numerically stable
__device__ __forceinline__ float sp2f(float x){
    float y = 0.5f * x;
    return 2.0f * (fmaxf(y, 0.0f) + log1pf(__expf(-fabsf(y))));
}
// ShiftSoftplus: softplus(x) - ln(2)
__device__ __forceinline__ float sspf(float x){
    return fmaxf(x, 0.0f) + log1pf(__expf(-fabsf(x))) - 0.69314718055994531f;
}

__global__ void k_embed(const int* __restrict__ types, const float* __restrict__ emb,
                        float* __restrict__ node){
    int i = blockIdx.x * 256 + threadIdx.x;
    if (i < N_NODES * DIM) node[i] = emb[types[i >> 6] * DIM + (i & 63)];
}

__global__ void k_counts(const int* __restrict__ gid, float* __restrict__ counts){
    int i = blockIdx.x * 256 + threadIdx.x;
    if (i < N_NODES) atomicAdd(&counts[gid[i]], 1.0f);
}

// ---------- CSR-by-dst build (once per launch, reused by all 3 conv layers) ----------
__global__ void k_hist(const int* __restrict__ edst, int* __restrict__ off){
    int e = blockIdx.x * 256 + threadIdx.x;
    if (e < N_EDGES) atomicAdd(&off[edst[e] + 1], 1);
}

// in-place inclusive scan of off[0..N_NODES]; also copies result into cursor[]
__global__ __launch_bounds__(1024) void k_scan(int* __restrict__ off, int* __restrict__ cursor){
    __shared__ int s_sum[1024];
    const int CH = 49;                       // 1024*49 = 50176 >= 50001
    int tid = threadIdx.x;
    int v[CH];
    int base = tid * CH;
    int run = 0;
    #pragma unroll
    for (int i = 0; i < CH; ++i){
        int idx = base + i;
        int x = (idx <= N_NODES) ? off[idx] : 0;
        run += x;
        v[i] = run;                          // inclusive within chunk
    }
    s_sum[tid] = run;
    __syncthreads();
    for (int d = 1; d < 1024; d <<= 1){
        int t = (tid >= d) ? s_sum[tid - d] : 0;
        __syncthreads();
        s_sum[tid] += t;
        __syncthreads();
    }
    int prefix = (tid > 0) ? s_sum[tid - 1] : 0;
    #pragma unroll
    for (int i = 0; i < CH; ++i){
        int idx = base + i;
        if (idx <= N_NODES){
            int val = prefix + v[i];
            off[idx] = val;
            cursor[idx] = val;
        }
    }
}

// scatter (dist, src) pairs into dst-sorted order; cursor[n] pre-seeded to off[n]
__global__ void k_scatter(const int* __restrict__ esrc, const int* __restrict__ edst,
                          const float* __restrict__ dist, int* __restrict__ cursor,
                          float2* __restrict__ edata){
    int e = blockIdx.x * 256 + threadIdx.x;
    if (e >= N_EDGES) return;
    int pos = atomicAdd(&cursor[edst[e]], 1);
    edata[pos] = make_float2(dist[e], __int_as_float(esrc[e]));
}

// ---------- per-layer filter table: tab[t][c] = eh(d_t)[c], d_t = t*5/(TAB-1) ----------
__global__ __launch_bounds__(256) void k_table(const float* __restrict__ cf1w,
    const float* __restrict__ cf1b, const float* __restrict__ cf2w,
    const float* __restrict__ cf2b, float* __restrict__ tab)
{
    __shared__ float s_cf1[RBF_DIM * 64];
    __shared__ float s_cf1b[64], s_cf2b[64];
    __shared__ float s_cf2[64 * 64];
    __shared__ float s_h1[4 * 64];
    int tid = threadIdx.x;
    int c = tid & 63, g = tid >> 6;
    for (int i = tid; i < 64 * 64; i += 256) s_cf2[i] = cf2w[i];
    for (int i = tid; i < RBF_DIM * 64; i += 256) s_cf1[i] = cf1w[i];
    if (tid < 64){ s_cf1b[tid] = cf1b[tid]; s_cf2b[tid] = cf2b[tid]; }
    __syncthreads();
    int entry = blockIdx.x * 4 + g;
    float d = (float)entry * (5.0f / (float)(TAB - 1));
    {
        float acc = s_cf1b[c];
        #pragma unroll
        for (int j = 0; j < RBF_DIM; ++j){
            float t = d - 1.25f * (float)j;        // centers = linspace(0,5,5)
            acc += __expf(-0.8f * t * t) * s_cf1[j * 64 + c];
        }
        s_h1[g * 64 + c] = sp2f(acc);
    }
    __syncthreads();
    {
        float acc = s_cf2b[c];
        #pragma unroll 8
        for (int k = 0; k < 64; ++k) acc += s_h1[g * 64 + k] * s_cf2[k * 64 + c];
        tab[entry * 64 + c] = sp2f(acc);
    }
}

// ---------- atomic-free aggregation: one 64-lane wave row per node ----------
__global__ __launch_bounds__(256) void k_agg(const float2* __restrict__ edata,
    const int* __restrict__ off, const float* __restrict__ tab,
    const float* __restrict__ new_node, float* __restrict__ agg)
{
    int tid = threadIdx.x;
    int c = tid & 63, r = tid >> 6;
    int n = blockIdx.x * 4 + r;
    if (n >= N_NODES) return;
    int e0 = off[n], e1 = off[n + 1];
    float acc = 0.f;
    for (int e = e0; e < e1; ++e){
        float2 ev = edata[e];
        float d = ev.x;
        int s = __float_as_int(ev.y);
        float x = d * ((float)(TAB - 1) / 5.0f);
        int i0 = (int)x;
        i0 = min(i0, TAB - 2);
        float f = x - (float)i0;
        float w0 = tab[i0 * 64 + c];
        float w1 = tab[i0 * 64 + 64 + c];
        float eh = w0 + (w1 - w0) * f;
        acc += new_node[s * 64 + c] * eh;
    }
    agg[n * 64 + c] = acc;
}

// out[n] = in[n] @ W   (64x64, W in LDS). 256 thr = 4 rows x 64 cols, 16 rows/block.
__global__ __launch_bounds__(256) void k_gemm64(const float* __restrict__ in,
                                                const float* __restrict__ W,
                                                float* __restrict__ out){
    __shared__ float sW[64 * 64];
    __shared__ float sIn[4 * 64];
    int tid = threadIdx.x;
    int c = tid & 63, r = tid >> 6;
    for (int i = tid; i < 64 * 64; i += 256) sW[i] = W[i];
    __syncthreads();
    int base = blockIdx.x * 16;
    for (int it = 0; it < 4; ++it){
        int n = base + it * 4 + r;
        bool ok = (n < N_NODES);
        if (ok) sIn[r * 64 + c] = in[n * 64 + c];
        __syncthreads();
        if (ok){
            float acc = 0.f;
            #pragma unroll 8
            for (int k = 0; k < 64; ++k) acc += sIn[r * 64 + k] * sW[k * 64 + c];
            out[n * 64 + c] = acc;
        }
        __syncthreads();
    }
}

// node += sp2(agg@nl2 + b2) @ nl3 + b3
__global__ __launch_bounds__(256) void k_update(const float* __restrict__ agg,
    const float* __restrict__ nl2w, const float* __restrict__ nl2b,
    const float* __restrict__ nl3w, const float* __restrict__ nl3b,
    float* __restrict__ node)
{
    __shared__ float s_w2[64 * 64], s_w3[64 * 64];
    __shared__ float s_b2[64], s_b3[64];
    __shared__ float s_in[4 * 64], s_t[4 * 64];
    int tid = threadIdx.x;
    int c = tid & 63, r = tid >> 6;
    for (int i = tid; i < 4096; i += 256){ s_w2[i] = nl2w[i]; s_w3[i] = nl3w[i]; }
    if (tid < 64){ s_b2[tid] = nl2b[tid]; s_b3[tid] = nl3b[tid]; }
    __syncthreads();
    int base = blockIdx.x * 16;
    for (int it = 0; it < 4; ++it){
        int n = base + it * 4 + r;
        bool ok = (n < N_NODES);
        if (ok) s_in[r * 64 + c] = agg[n * 64 + c];
        __syncthreads();
        if (ok){
            float acc = s_b2[c];
            #pragma unroll 8
            for (int k = 0; k < 64; ++k) acc += s_in[r * 64 + k] * s_w2[k * 64 + c];
            s_t[r * 64 + c] = sp2f(acc);
        }
        __syncthreads();
        if (ok){
            float acc = s_b3[c];
            #pragma unroll 8
            for (int k = 0; k < 64; ++k) acc += s_t[r * 64 + k] * s_w3[k * 64 + c];
            node[n * 64 + c] += acc;
        }
        __syncthreads();
    }
}

// Fused readout per 8 nodes: atom=ssp(node@d1+b); res=atom@d2+b;
// graph-pool atomicAdd(res); atoms_preds = relu(res)@ac + b.
__global__ __launch_bounds__(256) void k_readout(const float* __restrict__ node,
    const float* __restrict__ d1w, const float* __restrict__ d1b,
    const float* __restrict__ d2w, const float* __restrict__ d2b,
    const float* __restrict__ acw, const float* __restrict__ acb,
    const int* __restrict__ gid,
    float* __restrict__ gacc, float* __restrict__ out_atoms)
{
    __shared__ float s_node[8 * 64];
    __shared__ float s_atom[8 * 256];
    __shared__ float s_res[8 * 256];
    int tid = threadIdx.x;
    int base = blockIdx.x * 8;
    for (int i = tid; i < 8 * 64; i += 256){
        int n = base + (i >> 6);
        s_node[i] = (n < N_NODES) ? node[n * 64 + (i & 63)] : 0.f;
    }
    __syncthreads();
    { // stage 1: atom rows (col = tid)
        float acc[8];
        #pragma unroll
        for (int r = 0; r < 8; ++r) acc[r] = 0.f;
        for (int k = 0; k < 64; ++k){
            float w = d1w[k * 256 + tid];
            #pragma unroll
            for (int r = 0; r < 8; ++r) acc[r] += s_node[r * 64 + k] * w;
        }
        float b = d1b[tid];
        #pragma unroll
        for (int r = 0; r < 8; ++r) s_atom[r * 256 + tid] = sspf(acc[r] + b);
    }
    __syncthreads();
    { // stage 2: res rows + graph pool
        float acc[8];
        #pragma unroll
        for (int r = 0; r < 8; ++r) acc[r] = 0.f;
        for (int k = 0; k < 256; ++k){
            float w = d2w[k * 256 + tid];
            #pragma unroll
            for (int r = 0; r < 8; ++r) acc[r] += s_atom[r * 256 + k] * w;
        }
        float b = d2b[tid];
        #pragma unroll
        for (int r = 0; r < 8; ++r){
            int n = base + r;
            float v = acc[r] + b;
            s_res[r * 256 + tid] = fmaxf(v, 0.f);
            if (n < N_NODES) atomicAdd(&gacc[gid[n] * 256 + tid], v);
        }
    }
    __syncthreads();
    // stage 3: atoms_preds (8 rows x 100 cols as a task loop)
    for (int task = tid; task < 8 * ACT_DIM; task += 256){
        int r = task / ACT_DIM, j = task - r * ACT_DIM;
        int n = base + r;
        if (n >= N_NODES) continue;
        float acc = acb[j];
        for (int k = 0; k < 256; ++k) acc += s_res[r * 256 + k] * acw[k * ACT_DIM + j];
        out_atoms[n * ACT_DIM + j] = acc;
    }
}

__global__ __launch_bounds__(256) void k_cls(const float* __restrict__ gacc,
    const float* __restrict__ counts, const float* __restrict__ clsw,
    const float* __restrict__ clsb, float* __restrict__ out_cls)
{
    __shared__ float s_e[256];
    int g = blockIdx.x, tid = threadIdx.x;
    float cnt = fmaxf(counts[g], 1.0f);
    s_e[tid] = gacc[g * 256 + tid] / cnt;
    __syncthreads();
    for (int j = tid; j < CLS_DIM; j += 256){
        float acc = clsb[j];
        for (int k = 0; k < 256; ++k) acc += s_e[k] * clsw[k * CLS_DIM + j];
        out_cls[g * CLS_DIM + j] = acc;
    }
}

extern "C" void kernel_launch(void* const* d_in, const int* in_sizes, int n_in,
                              void* d_out, int out_size, void* d_ws, size_t ws_size,
                              hipStream_t stream)
{
    const int*   node_types = (const int*)d_in[0];
    const int*   edge_src   = (const int*)d_in[1];
    const int*   edge_dst   = (const int*)d_in[2];
    const int*   graph_ids  = (const int*)d_in[3];
    const float* distance   = (const float*)d_in[4];
    const float* emb        = (const float*)d_in[5];
    const float* conv_w1    = (const float*)d_in[6];
    const float* cf1_w      = (const float*)d_in[7];
    const float* cf1_b      = (const float*)d_in[8];
    const float* cf2_w      = (const float*)d_in[9];
    const float* cf2_b      = (const float*)d_in[10];
    const float* nl2_w      = (const float*)d_in[11];
    const float* nl2_b      = (const float*)d_in[12];
    const float* nl3_w      = (const float*)d_in[13];
    const float* nl3_b      = (const float*)d_in[14];
    const float* d1_w       = (const float*)d_in[15];
    const float* d1_b       = (const float*)d_in[16];
    const float* d2_w       = (const float*)d_in[17];
    const float* d2_b       = (const float*)d_in[18];
    const float* cls_w      = (const float*)d_in[19];
    const float* cls_b      = (const float*)d_in[20];
    const float* ac_w       = (const float*)d_in[21];
    const float* ac_b       = (const float*)d_in[22];

    // workspace layout
    float* ws       = (float*)d_ws;
    float* node     = ws;                          // N*64           = 3.20M f
    float* new_node = node + N_NODES * DIM;        // N*64           = 3.20M f
    float* agg      = new_node + N_NODES * DIM;    // N*64           = 3.20M f
    float* gacc     = agg + N_NODES * DIM;         // 500*256        = 128k f
    float* counts   = gacc + N_GRAPHS * HID;       // 500 f
    float* tab      = counts + 512;                // TAB*64         = 131k f
    int*   off      = (int*)(tab + TAB * 64);      // N+1 ints
    int*   cursor   = off + (N_NODES + 1);         // N+1 ints
    float2* edata   = (float2*)(cursor + (N_NODES + 1)); // E float2 = 6.4 MB
    float* out      = (float*)d_out;
    // total ≈ 46.3 MB

    hipMemsetAsync(gacc, 0, (N_GRAPHS * HID + N_GRAPHS) * sizeof(float), stream);
    hipMemsetAsync(off, 0, (N_NODES + 1) * sizeof(int), stream);

    k_embed<<<(N_NODES * DIM + 255) / 256, 256, 0, stream>>>(node_types, emb, node);
    k_counts<<<(N_NODES + 255) / 256, 256, 0, stream>>>(graph_ids, counts);

    // CSR-by-dst build (reused by all 3 layers)
    k_hist<<<(N_EDGES + 255) / 256, 256, 0, stream>>>(edge_dst, off);
    k_scan<<<1, 1024, 0, stream>>>(off, cursor);
    k_scatter<<<(N_EDGES + 255) / 256, 256, 0, stream>>>(edge_src, edge_dst, distance,
                                                         cursor, edata);

    for (int i = 0; i < N_CONV; ++i){
        k_gemm64<<<(N_NODES + 15) / 16, 256, 0, stream>>>(node, conv_w1 + i * DIM * DIM, new_node);
        k_table<<<TAB / 4, 256, 0, stream>>>(cf1_w + i * RBF_DIM * DIM, cf1_b + i * DIM,
                                             cf2_w + i * DIM * DIM, cf2_b + i * DIM, tab);
        k_agg<<<(N_NODES + 3) / 4, 256, 0, stream>>>(edata, off, tab, new_node, agg);
        k_update<<<(N_NODES + 15) / 16, 256, 0, stream>>>(agg,
            nl2_w + i * DIM * DIM, nl2_b + i * DIM,
            nl3_w + i * DIM * DIM, nl3_b + i * DIM, node);
    }

    k_readout<<<(N_NODES + 7) / 8, 256, 0, stream>>>(node, d1_w, d1_b, d2_w, d2_b,
        ac_w, ac_b, graph_ids, gacc, out);
    k_cls<<<N_GRAPHS, 256, 0, stream>>>(gacc, counts, cls_w, cls_b, out + N_NODES * ACT_DIM);
}

// Round 5
// 899.988 us; speedup vs baseline: 2.2135x; 1.3711x over previous
//
#include <hip/hip_runtime.h>
#include <math.h>

#define N_NODES 50000
#define N_EDGES 800000
#define N_GRAPHS 500
#define DIM 64
#define RBF_DIM 5
#define N_CONV 3
#define CLS_DIM 2000
#define ACT_DIM 100
#define HID 256
#define TAB 2048

typedef __attribute__((ext_vector_type(8))) short bf16x8;
typedef __attribute__((ext_vector_type(4))) float f32x4;
#define MFMA16(a,b,c) __builtin_amdgcn_mfma_f32_16x16x32_bf16(a,b,c,0,0,0)

__device__ __forceinline__ float sp2f(float x){
    float y = 0.5f * x;
    return 2.0f * (fmaxf(y, 0.0f) + log1pf(__expf(-fabsf(y))));
}
__device__ __forceinline__ float sspf(float x){
    return fmaxf(x, 0.0f) + log1pf(__expf(-fabsf(x))) - 0.69314718055994531f;
}
// fp32 -> bf16 (RNE)
__device__ __forceinline__ short f2b(float x){
    union { float f; unsigned u; } v; v.f = x;
    unsigned r = v.u + 0x7FFFu + ((v.u >> 16) & 1u);
    return (short)(r >> 16);
}
__device__ __forceinline__ float b2f(short x){
    union { unsigned u; float f; } v; v.u = ((unsigned)(unsigned short)x) << 16;
    return v.f;
}

__global__ void k_embed(const int* __restrict__ types, const float* __restrict__ emb,
                        float* __restrict__ node, short* __restrict__ nodeb){
    int i = blockIdx.x * 256 + threadIdx.x;
    if (i < N_NODES * DIM){
        float v = emb[types[i >> 6] * DIM + (i & 63)];
        node[i] = v; nodeb[i] = f2b(v);
    }
}

__global__ void k_counts(const int* __restrict__ gid, float* __restrict__ counts){
    int i = blockIdx.x * 256 + threadIdx.x;
    if (i < N_NODES) atomicAdd(&counts[gid[i]], 1.0f);
}

// ---------- CSR-by-dst build ----------
__global__ void k_hist(const int* __restrict__ edst, int* __restrict__ off){
    int e = blockIdx.x * 256 + threadIdx.x;
    if (e < N_EDGES) atomicAdd(&off[edst[e] + 1], 1);
}

__global__ __launch_bounds__(1024) void k_scan(int* __restrict__ off, int* __restrict__ cursor){
    __shared__ int s_sum[1024];
    const int CH = 49;
    int tid = threadIdx.x;
    int v[CH];
    int base = tid * CH;
    int run = 0;
    #pragma unroll
    for (int i = 0; i < CH; ++i){
        int idx = base + i;
        int x = (idx <= N_NODES) ? off[idx] : 0;
        run += x; v[i] = run;
    }
    s_sum[tid] = run;
    __syncthreads();
    for (int d = 1; d < 1024; d <<= 1){
        int t = (tid >= d) ? s_sum[tid - d] : 0;
        __syncthreads();
        s_sum[tid] += t;
        __syncthreads();
    }
    int prefix = (tid > 0) ? s_sum[tid - 1] : 0;
    #pragma unroll
    for (int i = 0; i < CH; ++i){
        int idx = base + i;
        if (idx <= N_NODES){ int val = prefix + v[i]; off[idx] = val; cursor[idx] = val; }
    }
}

__global__ void k_scatter(const int* __restrict__ esrc, const int* __restrict__ edst,
                          const float* __restrict__ dist, int* __restrict__ cursor,
                          float2* __restrict__ edata){
    int e = blockIdx.x * 256 + threadIdx.x;
    if (e >= N_EDGES) return;
    int pos = atomicAdd(&cursor[edst[e]], 1);
    edata[pos] = make_float2(dist[e], __int_as_float(esrc[e]));
}

// ---------- weight cast+transpose: out_t[n*K+k] = bf16(in[k*N+n]) ----------
// nine 64x64 mats: y in 0..8 -> {conv_w1, nl2_w, nl3_w}[y/3], layer y%3
__global__ void k_t64(const float* __restrict__ cw, const float* __restrict__ n2,
                      const float* __restrict__ n3, short* __restrict__ cwt,
                      short* __restrict__ n2t, short* __restrict__ n3t){
    int y = blockIdx.y, which = y / 3, layer = y % 3;
    const float* src = (which == 0 ? cw : which == 1 ? n2 : n3) + layer * 4096;
    short* dst = (which == 0 ? cwt : which == 1 ? n2t : n3t) + layer * 4096;
    int i = blockIdx.x * 256 + threadIdx.x;      // 4096 total
    int k = i >> 6, n = i & 63;
    dst[n * 64 + k] = f2b(src[k * 64 + n]);
}

// y=0: d1 (K=64,N=256); y=1: d2 (256,256); y=2: ac (K=256,N=100 pad->112)
__global__ void k_tbig(const float* __restrict__ d1w, const float* __restrict__ d2w,
                       const float* __restrict__ acw, short* __restrict__ d1t,
                       short* __restrict__ d2t, short* __restrict__ act){
    int y = blockIdx.y;
    int i = blockIdx.x * 256 + threadIdx.x;
    if (y == 0){ if (i < 64 * 256){ int k = i >> 8, n = i & 255; d1t[n * 64 + k] = f2b(d1w[k * 256 + n]); } }
    else if (y == 1){ if (i < 256 * 256){ int k = i >> 8, n = i & 255; d2t[n * 256 + k] = f2b(d2w[k * 256 + n]); } }
    else { if (i < 112 * 256){ int n = i >> 8, k = i & 255; act[n * 256 + k] = f2b(n < ACT_DIM ? acw[k * ACT_DIM + n] : 0.f); } }
}

// ---------- per-layer filter table (bf16 out) ----------
__global__ __launch_bounds__(256) void k_table(const float* __restrict__ cf1w,
    const float* __restrict__ cf1b, const float* __restrict__ cf2w,
    const float* __restrict__ cf2b, short* __restrict__ tabb)
{
    __shared__ float s_cf1[RBF_DIM * 64];
    __shared__ float s_cf1b[64], s_cf2b[64];
    __shared__ float s_cf2[64 * 64];
    __shared__ float s_h1[4 * 64];
    int tid = threadIdx.x;
    int c = tid & 63, g = tid >> 6;
    for (int i = tid; i < 64 * 64; i += 256) s_cf2[i] = cf2w[i];
    for (int i = tid; i < RBF_DIM * 64; i += 256) s_cf1[i] = cf1w[i];
    if (tid < 64){ s_cf1b[tid] = cf1b[tid]; s_cf2b[tid] = cf2b[tid]; }
    __syncthreads();
    int entry = blockIdx.x * 4 + g;
    float d = (float)entry * (5.0f / (float)(TAB - 1));
    {
        float acc = s_cf1b[c];
        #pragma unroll
        for (int j = 0; j < RBF_DIM; ++j){
            float t = d - 1.25f * (float)j;
            acc += __expf(-0.8f * t * t) * s_cf1[j * 64 + c];
        }
        s_h1[g * 64 + c] = sp2f(acc);
    }
    __syncthreads();
    {
        float acc = s_cf2b[c];
        #pragma unroll 8
        for (int k = 0; k < 64; ++k) acc += s_h1[g * 64 + k] * s_cf2[k * 64 + c];
        tabb[entry * 64 + c] = f2b(sp2f(acc));
    }
}

// ---------- aggregation (bf16 gathers, fp32 accum, bf16 out) ----------
__global__ __launch_bounds__(256) void k_agg(const float2* __restrict__ edata,
    const int* __restrict__ off, const short* __restrict__ tabb,
    const short* __restrict__ nnb, short* __restrict__ aggb)
{
    int tid = threadIdx.x;
    int c = tid & 63, r = tid >> 6;
    int n = blockIdx.x * 4 + r;
    if (n >= N_NODES) return;
    int e0 = off[n], e1 = off[n + 1];
    float acc = 0.f;
    for (int e = e0; e < e1; ++e){
        float2 ev = edata[e];
        float d = ev.x;
        int s = __float_as_int(ev.y);
        float x = d * ((float)(TAB - 1) / 5.0f);
        int i0 = (int)x;
        i0 = min(i0, TAB - 2);
        float f = x - (float)i0;
        float w0 = b2f(tabb[i0 * 64 + c]);
        float w1 = b2f(tabb[i0 * 64 + 64 + c]);
        acc += b2f(nnb[s * 64 + c]) * (w0 + (w1 - w0) * f);
    }
    aggb[n * 64 + c] = f2b(acc);
}

// ---------- MFMA: new_node = node @ conv_w1  (64 rows/block) ----------
__global__ __launch_bounds__(256) void k_gemm64(const short* __restrict__ nodeb,
    const short* __restrict__ wt, short* __restrict__ outb)
{
    int tid = threadIdx.x, wave = tid >> 6, lane = tid & 63;
    int quad = lane >> 4, l16 = lane & 15;
    int row0 = blockIdx.x * 64;
    f32x4 acc[4] = {{0,0,0,0},{0,0,0,0},{0,0,0,0},{0,0,0,0}};
    #pragma unroll
    for (int kt = 0; kt < 2; ++kt){
        int k0 = kt * 32 + quad * 8;
        int rw = row0 + wave * 16 + l16;
        bf16x8 a = (rw < N_NODES) ? *(const bf16x8*)&nodeb[rw * 64 + k0] : (bf16x8){0,0,0,0,0,0,0,0};
        #pragma unroll
        for (int ct = 0; ct < 4; ++ct){
            bf16x8 b = *(const bf16x8*)&wt[(ct * 16 + l16) * 64 + k0];
            acc[ct] = MFMA16(a, b, acc[ct]);
        }
    }
    #pragma unroll
    for (int ct = 0; ct < 4; ++ct)
        #pragma unroll
        for (int reg = 0; reg < 4; ++reg){
            int row = row0 + wave * 16 + quad * 4 + reg;
            if (row < N_NODES) outb[row * 64 + (ct * 16 + l16)] = f2b(acc[ct][reg]);
        }
}

// ---------- MFMA update: node += sp2(agg@nl2+b2)@nl3 + b3 (32 rows/block) ----------
__global__ __launch_bounds__(256) void k_update(const short* __restrict__ aggb,
    const short* __restrict__ nl2t, const float* __restrict__ nl2b,
    const short* __restrict__ nl3t, const float* __restrict__ nl3b,
    float* __restrict__ node, short* __restrict__ nodeb)
{
    __shared__ short sT[32 * 80];        // t tile [32 rows][64 k], stride 80
    int tid = threadIdx.x, wave = tid >> 6, lane = tid & 63;
    int quad = lane >> 4, l16 = lane & 15;
    int row0 = blockIdx.x * 32;
    int rt = wave >> 1;                  // 0..1
    int ctb = (wave & 1) * 2;            // 0 or 2
    // stage 1
    f32x4 acc[2] = {{0,0,0,0},{0,0,0,0}};
    #pragma unroll
    for (int kt = 0; kt < 2; ++kt){
        int k0 = kt * 32 + quad * 8;
        int rw = row0 + rt * 16 + l16;
        bf16x8 a = (rw < N_NODES) ? *(const bf16x8*)&aggb[rw * 64 + k0] : (bf16x8){0,0,0,0,0,0,0,0};
        #pragma unroll
        for (int i = 0; i < 2; ++i){
            bf16x8 b = *(const bf16x8*)&nl2t[((ctb + i) * 16 + l16) * 64 + k0];
            acc[i] = MFMA16(a, b, acc[i]);
        }
    }
    #pragma unroll
    for (int i = 0; i < 2; ++i)
        #pragma unroll
        for (int reg = 0; reg < 4; ++reg){
            int rl = rt * 16 + quad * 4 + reg;
            int col = (ctb + i) * 16 + l16;
            sT[rl * 80 + col] = f2b(sp2f(acc[i][reg] + nl2b[col]));
        }
    __syncthreads();
    // stage 2
    f32x4 acc2[2] = {{0,0,0,0},{0,0,0,0}};
    #pragma unroll
    for (int kt = 0; kt < 2; ++kt){
        int k0 = kt * 32 + quad * 8;
        bf16x8 a = *(const bf16x8*)&sT[(rt * 16 + l16) * 80 + k0];
        #pragma unroll
        for (int i = 0; i < 2; ++i){
            bf16x8 b = *(const bf16x8*)&nl3t[((ctb + i) * 16 + l16) * 64 + k0];
            acc2[i] = MFMA16(a, b, acc2[i]);
        }
    }
    #pragma unroll
    for (int i = 0; i < 2; ++i)
        #pragma unroll
        for (int reg = 0; reg < 4; ++reg){
            int row = row0 + rt * 16 + quad * 4 + reg;
            int col = (ctb + i) * 16 + l16;
            if (row < N_NODES){
                float v = node[row * 64 + col] + acc2[i][reg] + nl3b[col];
                node[row * 64 + col] = v;
                nodeb[row * 64 + col] = f2b(v);
            }
        }
}

// ---------- readout stage 1: atom = ssp(node@d1+b1), bf16 out (32 rows/block) ----------
__global__ __launch_bounds__(256) void k_r1(const short* __restrict__ nodeb,
    const short* __restrict__ d1t, const float* __restrict__ d1b,
    short* __restrict__ atomb)
{
    int tid = threadIdx.x, wave = tid >> 6, lane = tid & 63;
    int quad = lane >> 4, l16 = lane & 15;
    int row0 = blockIdx.x * 32;
    f32x4 acc[2][4] = {{{0,0,0,0},{0,0,0,0},{0,0,0,0},{0,0,0,0}},
                       {{0,0,0,0},{0,0,0,0},{0,0,0,0},{0,0,0,0}}};
    #pragma unroll
    for (int kt = 0; kt < 2; ++kt){
        int k0 = kt * 32 + quad * 8;
        bf16x8 a[2];
        #pragma unroll
        for (int rt = 0; rt < 2; ++rt){
            int rw = row0 + rt * 16 + l16;
            a[rt] = (rw < N_NODES) ? *(const bf16x8*)&nodeb[rw * 64 + k0] : (bf16x8){0,0,0,0,0,0,0,0};
        }
        #pragma unroll
        for (int ct = 0; ct < 4; ++ct){
            int n = wave * 64 + ct * 16 + l16;
            bf16x8 b = *(const bf16x8*)&d1t[n * 64 + k0];
            #pragma unroll
            for (int rt = 0; rt < 2; ++rt) acc[rt][ct] = MFMA16(a[rt], b, acc[rt][ct]);
        }
    }
    #pragma unroll
    for (int rt = 0; rt < 2; ++rt)
        #pragma unroll
        for (int ct = 0; ct < 4; ++ct){
            int col = wave * 64 + ct * 16 + l16;
            float bb = d1b[col];
            #pragma unroll
            for (int reg = 0; reg < 4; ++reg){
                int row = row0 + rt * 16 + quad * 4 + reg;
                if (row < N_NODES) atomb[row * HID + col] = f2b(sspf(acc[rt][ct][reg] + bb));
            }
        }
}

// ---------- readout stage 2: res = atom@d2+b2; pool to gacc; resb = bf16(relu(res)) ----------
__global__ __launch_bounds__(256) void k_r2(const short* __restrict__ atomb,
    const short* __restrict__ d2t, const float* __restrict__ d2b_,
    const int* __restrict__ gid, float* __restrict__ gacc, short* __restrict__ resb)
{
    __shared__ float sres[32 * 260];
    int tid = threadIdx.x, wave = tid >> 6, lane = tid & 63;
    int quad = lane >> 4, l16 = lane & 15;
    int row0 = blockIdx.x * 32;
    f32x4 acc[2][4] = {{{0,0,0,0},{0,0,0,0},{0,0,0,0},{0,0,0,0}},
                       {{0,0,0,0},{0,0,0,0},{0,0,0,0},{0,0,0,0}}};
    for (int kt = 0; kt < 8; ++kt){
        int k0 = kt * 32 + quad * 8;
        bf16x8 a[2];
        #pragma unroll
        for (int rt = 0; rt < 2; ++rt){
            int rw = row0 + rt * 16 + l16;
            a[rt] = (rw < N_NODES) ? *(const bf16x8*)&atomb[rw * HID + k0] : (bf16x8){0,0,0,0,0,0,0,0};
        }
        #pragma unroll
        for (int ct = 0; ct < 4; ++ct){
            int n = wave * 64 + ct * 16 + l16;
            bf16x8 b = *(const bf16x8*)&d2t[n * HID + k0];
            #pragma unroll
            for (int rt = 0; rt < 2; ++rt) acc[rt][ct] = MFMA16(a[rt], b, acc[rt][ct]);
        }
    }
    #pragma unroll
    for (int rt = 0; rt < 2; ++rt)
        #pragma unroll
        for (int ct = 0; ct < 4; ++ct){
            int col = wave * 64 + ct * 16 + l16;
            float bb = d2b_[col];
            #pragma unroll
            for (int reg = 0; reg < 4; ++reg){
                int rl = rt * 16 + quad * 4 + reg;
                sres[rl * 260 + col] = acc[rt][ct][reg] + bb;
            }
        }
    __syncthreads();
    // pooling (pre-relu) with run-length compression over sorted gid + relu->bf16 store
    float run = 0.f; int cur = -1;
    for (int r = 0; r < 32; ++r){
        int n = row0 + r;
        if (n >= N_NODES) break;
        float v = sres[r * 260 + tid];
        int g = gid[n];
        if (g != cur){
            if (cur >= 0) atomicAdd(&gacc[cur * HID + tid], run);
            run = 0.f; cur = g;
        }
        run += v;
        resb[n * HID + tid] = f2b(fmaxf(v, 0.f));
    }
    if (cur >= 0) atomicAdd(&gacc[cur * HID + tid], run);
}

// ---------- readout stage 3: atoms_preds = resb@ac + b (64 rows/block, N=112 padded) ----------
__global__ __launch_bounds__(256) void k_r3(const short* __restrict__ resb,
    const short* __restrict__ act, const float* __restrict__ acb,
    float* __restrict__ out_atoms)
{
    int tid = threadIdx.x, wave = tid >> 6, lane = tid & 63;
    int quad = lane >> 4, l16 = lane & 15;
    int row0 = blockIdx.x * 64;
    f32x4 acc[7] = {{0,0,0,0},{0,0,0,0},{0,0,0,0},{0,0,0,0},{0,0,0,0},{0,0,0,0},{0,0,0,0}};
    for (int kt = 0; kt < 8; ++kt){
        int k0 = kt * 32 + quad * 8;
        int rw = row0 + wave * 16 + l16;
        bf16x8 a = (rw < N_NODES) ? *(const bf16x8*)&resb[rw * HID + k0] : (bf16x8){0,0,0,0,0,0,0,0};
        #pragma unroll
        for (int ct = 0; ct < 7; ++ct){
            bf16x8 b = *(const bf16x8*)&act[(ct * 16 + l16) * HID + k0];
            acc[ct] = MFMA16(a, b, acc[ct]);
        }
    }
    #pragma unroll
    for (int ct = 0; ct < 7; ++ct){
        int col = ct * 16 + l16;
        if (col >= ACT_DIM) continue;
        float bb = acb[col];
        #pragma unroll
        for (int reg = 0; reg < 4; ++reg){
            int row = row0 + wave * 16 + quad * 4 + reg;
            if (row < N_NODES) out_atoms[row * ACT_DIM + col] = acc[ct][reg] + bb;
        }
    }
}

__global__ __launch_bounds__(256) void k_cls(const float* __restrict__ gacc,
    const float* __restrict__ counts, const float* __restrict__ clsw,
    const float* __restrict__ clsb, float* __restrict__ out_cls)
{
    __shared__ float s_e[256];
    int g = blockIdx.x, tid = threadIdx.x;
    float cnt = fmaxf(counts[g], 1.0f);
    s_e[tid] = gacc[g * 256 + tid] / cnt;
    __syncthreads();
    for (int j = tid; j < CLS_DIM; j += 256){
        float acc = clsb[j];
        for (int k = 0; k < 256; ++k) acc += s_e[k] * clsw[k * CLS_DIM + j];
        out_cls[g * CLS_DIM + j] = acc;
    }
}

extern "C" void kernel_launch(void* const* d_in, const int* in_sizes, int n_in,
                              void* d_out, int out_size, void* d_ws, size_t ws_size,
                              hipStream_t stream)
{
    const int*   node_types = (const int*)d_in[0];
    const int*   edge_src   = (const int*)d_in[1];
    const int*   edge_dst   = (const int*)d_in[2];
    const int*   graph_ids  = (const int*)d_in[3];
    const float* distance   = (const float*)d_in[4];
    const float* emb        = (const float*)d_in[5];
    const float* conv_w1    = (const float*)d_in[6];
    const float* cf1_w      = (const float*)d_in[7];
    const float* cf1_b      = (const float*)d_in[8];
    const float* cf2_w      = (const float*)d_in[9];
    const float* cf2_b      = (const float*)d_in[10];
    const float* nl2_w      = (const float*)d_in[11];
    const float* nl2_b      = (const float*)d_in[12];
    const float* nl3_w      = (const float*)d_in[13];
    const float* nl3_b      = (const float*)d_in[14];
    const float* d1_w       = (const float*)d_in[15];
    const float* d1_b       = (const float*)d_in[16];
    const float* d2_w       = (const float*)d_in[17];
    const float* d2_b       = (const float*)d_in[18];
    const float* cls_w      = (const float*)d_in[19];
    const float* cls_b      = (const float*)d_in[20];
    const float* ac_w       = (const float*)d_in[21];
    const float* ac_b       = (const float*)d_in[22];

    // ---- workspace layout (all 16B-aligned; ~65.5 MB total) ----
    float*  node   = (float*)d_ws;                 // 3,200,000 f
    float*  gacc   = node + 3200000;               // 128,000 f
    float*  counts = gacc + 128000;                // 512 f
    float2* edata  = (float2*)(counts + 512);      // 800,000 f2
    int*    off    = (int*)(edata + 800000);       // 50,001 i
    int*    cursor = off + 50001;                  // 50,003 i (padded for align)
    short*  nodeb  = (short*)(cursor + 50003);     // 3,200,000
    short*  nnb    = nodeb + 3200000;              // 3,200,000
    short*  aggb   = nnb + 3200000;                // 3,200,000
    short*  atomb  = aggb + 3200000;               // 12,800,000
    short*  resb   = atomb;                        // ALIAS: safe — k_r2 block reads its
                                                   // atom rows (all consumed by MFMA)
                                                   // before writing resb to same rows
    short*  tabb   = atomb + 12800000;             // 131,072
    short*  cw1t   = tabb + 131072;                // 12,288
    short*  n2t    = cw1t + 12288;                 // 12,288
    short*  n3t    = n2t + 12288;                  // 12,288
    short*  d1t    = n3t + 12288;                  // 16,384
    short*  d2t    = d1t + 16384;                  // 65,536
    short*  act    = d2t + 65536;                  // 28,672
    float*  out    = (float*)d_out;

    (void)hipMemsetAsync(gacc, 0, (128000 + 512) * sizeof(float), stream);
    (void)hipMemsetAsync(off, 0, (N_NODES + 1) * sizeof(int), stream);

    k_t64<<<dim3(16, 9), 256, 0, stream>>>(conv_w1, nl2_w, nl3_w, cw1t, n2t, n3t);
    k_tbig<<<dim3(256, 3), 256, 0, stream>>>(d1_w, d2_w, ac_w, d1t, d2t, act);

    k_embed<<<(N_NODES * DIM + 255) / 256, 256, 0, stream>>>(node_types, emb, node, nodeb);
    k_counts<<<(N_NODES + 255) / 256, 256, 0, stream>>>(graph_ids, counts);
    k_hist<<<(N_EDGES + 255) / 256, 256, 0, stream>>>(edge_dst, off);
    k_scan<<<1, 1024, 0, stream>>>(off, cursor);
    k_scatter<<<(N_EDGES + 255) / 256, 256, 0, stream>>>(edge_src, edge_dst, distance,
                                                         cursor, edata);

    for (int i = 0; i < N_CONV; ++i){
        k_gemm64<<<(N_NODES + 63) / 64, 256, 0, stream>>>(nodeb, cw1t + i * 4096, nnb);
        k_table<<<TAB / 4, 256, 0, stream>>>(cf1_w + i * RBF_DIM * DIM, cf1_b + i * DIM,
                                             cf2_w + i * DIM * DIM, cf2_b + i * DIM, tabb);
        k_agg<<<(N_NODES + 3) / 4, 256, 0, stream>>>(edata, off, tabb, nnb, aggb);
        k_update<<<(N_NODES + 31) / 32, 256, 0, stream>>>(aggb,
            n2t + i * 4096, nl2_b + i * DIM, n3t + i * 4096, nl3_b + i * DIM, node, nodeb);
    }

    k_r1<<<(N_NODES + 31) / 32, 256, 0, stream>>>(nodeb, d1t, d1_b, atomb);
    k_r2<<<(N_NODES + 31) / 32, 256, 0, stream>>>(atomb, d2t, d2_b, graph_ids, gacc, resb);
    k_r3<<<(N_NODES + 63) / 64, 256, 0, stream>>>(resb, act, ac_b, out);
    k_cls<<<N_GRAPHS, 256, 0, stream>>>(gacc, counts, cls_w, cls_b, out + N_NODES * ACT_DIM);
}

// Round 6
// 726.528 us; speedup vs baseline: 2.7420x; 1.2388x over previous
//
#include <hip/hip_runtime.h>
#include <math.h>

#define N_NODES 50000
#define N_EDGES 800000
#define N_GRAPHS 500
#define DIM 64
#define RBF_DIM 5
#define N_CONV 3
#define CLS_DIM 2000
#define ACT_DIM 100
#define HID 256
#define TAB 2048

typedef __attribute__((ext_vector_type(8))) short bf16x8;
typedef __attribute__((ext_vector_type(4))) float f32x4;
#define MFMA16(a,b,c) __builtin_amdgcn_mfma_f32_16x16x32_bf16(a,b,c,0,0,0)

__device__ __forceinline__ float sp2f(float x){
    float y = 0.5f * x;
    return 2.0f * (fmaxf(y, 0.0f) + log1pf(__expf(-fabsf(y))));
}
__device__ __forceinline__ float sspf(float x){
    return fmaxf(x, 0.0f) + log1pf(__expf(-fabsf(x))) - 0.69314718055994531f;
}
// fp32 -> bf16 (RNE)
__device__ __forceinline__ short f2b(float x){
    union { float f; unsigned u; } v; v.f = x;
    unsigned r = v.u + 0x7FFFu + ((v.u >> 16) & 1u);
    return (short)(r >> 16);
}
__device__ __forceinline__ float b2f(short x){
    union { unsigned u; float f; } v; v.u = ((unsigned)(unsigned short)x) << 16;
    return v.f;
}

__global__ void k_embed(const int* __restrict__ types, const float* __restrict__ emb,
                        float* __restrict__ node, short* __restrict__ nodeb){
    int i = blockIdx.x * 256 + threadIdx.x;
    if (i < N_NODES * DIM){
        float v = emb[types[i >> 6] * DIM + (i & 63)];
        node[i] = v; nodeb[i] = f2b(v);
    }
}

__global__ void k_counts(const int* __restrict__ gid, float* __restrict__ counts){
    int i = blockIdx.x * 256 + threadIdx.x;
    if (i < N_NODES) atomicAdd(&counts[gid[i]], 1.0f);
}

// ---------- CSR-by-dst build ----------
__global__ void k_hist(const int* __restrict__ edst, int* __restrict__ off){
    int e = blockIdx.x * 256 + threadIdx.x;
    if (e < N_EDGES) atomicAdd(&off[edst[e] + 1], 1);
}

__global__ __launch_bounds__(1024) void k_scan(int* __restrict__ off, int* __restrict__ cursor){
    __shared__ int s_sum[1024];
    const int CH = 49;
    int tid = threadIdx.x;
    int v[CH];
    int base = tid * CH;
    int run = 0;
    #pragma unroll
    for (int i = 0; i < CH; ++i){
        int idx = base + i;
        int x = (idx <= N_NODES) ? off[idx] : 0;
        run += x; v[i] = run;
    }
    s_sum[tid] = run;
    __syncthreads();
    for (int d = 1; d < 1024; d <<= 1){
        int t = (tid >= d) ? s_sum[tid - d] : 0;
        __syncthreads();
        s_sum[tid] += t;
        __syncthreads();
    }
    int prefix = (tid > 0) ? s_sum[tid - 1] : 0;
    #pragma unroll
    for (int i = 0; i < CH; ++i){
        int idx = base + i;
        if (idx <= N_NODES){ int val = prefix + v[i]; off[idx] = val; cursor[idx] = val; }
    }
}

__global__ void k_scatter(const int* __restrict__ esrc, const int* __restrict__ edst,
                          const float* __restrict__ dist, int* __restrict__ cursor,
                          float2* __restrict__ edata){
    int e = blockIdx.x * 256 + threadIdx.x;
    if (e >= N_EDGES) return;
    int pos = atomicAdd(&cursor[edst[e]], 1);
    edata[pos] = make_float2(dist[e], __int_as_float(esrc[e]));
}

// ---------- weight cast+transpose: out_t[n*K+k] = bf16(in[k*N+n]) ----------
__global__ void k_t64(const float* __restrict__ cw, const float* __restrict__ n2,
                      const float* __restrict__ n3, short* __restrict__ cwt,
                      short* __restrict__ n2t, short* __restrict__ n3t){
    int y = blockIdx.y, which = y / 3, layer = y % 3;
    const float* src = (which == 0 ? cw : which == 1 ? n2 : n3) + layer * 4096;
    short* dst = (which == 0 ? cwt : which == 1 ? n2t : n3t) + layer * 4096;
    int i = blockIdx.x * 256 + threadIdx.x;
    int k = i >> 6, n = i & 63;
    dst[n * 64 + k] = f2b(src[k * 64 + n]);
}

// y=0: d1 (K=64,N=256); y=1: d2 (256,256); y=2: ac (K=256,N=100 pad->112)
__global__ void k_tbig(const float* __restrict__ d1w, const float* __restrict__ d2w,
                       const float* __restrict__ acw, short* __restrict__ d1t,
                       short* __restrict__ d2t, short* __restrict__ act){
    int y = blockIdx.y;
    int i = blockIdx.x * 256 + threadIdx.x;
    if (y == 0){ if (i < 64 * 256){ int k = i >> 8, n = i & 255; d1t[n * 64 + k] = f2b(d1w[k * 256 + n]); } }
    else if (y == 1){ if (i < 256 * 256){ int k = i >> 8, n = i & 255; d2t[n * 256 + k] = f2b(d2w[k * 256 + n]); } }
    else { if (i < 112 * 256){ int n = i >> 8, k = i & 255; act[n * 256 + k] = f2b(n < ACT_DIM ? acw[k * ACT_DIM + n] : 0.f); } }
}

// cls_w [256][2000] -> clswt [2048][256] bf16 (coalesced reads; scattered writes L2-absorbed)
__global__ void k_tcls(const float* __restrict__ clsw, short* __restrict__ clswt){
    int i = blockIdx.x * 256 + threadIdx.x;       // 256*2048 total, k-major
    int k = i >> 11, n = i & 2047;
    clswt[n * 256 + k] = f2b(n < CLS_DIM ? clsw[k * CLS_DIM + n] : 0.f);
}

// emb_g = gacc / counts -> bf16 [500][256]
__global__ void k_embg(const float* __restrict__ gacc, const float* __restrict__ counts,
                       short* __restrict__ gclsb){
    int i = blockIdx.x * 256 + threadIdx.x;       // 128000
    if (i < N_GRAPHS * HID){
        int g = i >> 8;
        gclsb[i] = f2b(gacc[i] / fmaxf(counts[g], 1.0f));
    }
}

// ---------- per-layer filter table (bf16 out) ----------
__global__ __launch_bounds__(256) void k_table(const float* __restrict__ cf1w,
    const float* __restrict__ cf1b, const float* __restrict__ cf2w,
    const float* __restrict__ cf2b, short* __restrict__ tabb)
{
    __shared__ float s_cf1[RBF_DIM * 64];
    __shared__ float s_cf1b[64], s_cf2b[64];
    __shared__ float s_cf2[64 * 64];
    __shared__ float s_h1[4 * 64];
    int tid = threadIdx.x;
    int c = tid & 63, g = tid >> 6;
    for (int i = tid; i < 64 * 64; i += 256) s_cf2[i] = cf2w[i];
    for (int i = tid; i < RBF_DIM * 64; i += 256) s_cf1[i] = cf1w[i];
    if (tid < 64){ s_cf1b[tid] = cf1b[tid]; s_cf2b[tid] = cf2b[tid]; }
    __syncthreads();
    int entry = blockIdx.x * 4 + g;
    float d = (float)entry * (5.0f / (float)(TAB - 1));
    {
        float acc = s_cf1b[c];
        #pragma unroll
        for (int j = 0; j < RBF_DIM; ++j){
            float t = d - 1.25f * (float)j;
            acc += __expf(-0.8f * t * t) * s_cf1[j * 64 + c];
        }
        s_h1[g * 64 + c] = sp2f(acc);
    }
    __syncthreads();
    {
        float acc = s_cf2b[c];
        #pragma unroll 8
        for (int k = 0; k < 64; ++k) acc += s_h1[g * 64 + k] * s_cf2[k * 64 + c];
        tabb[entry * 64 + c] = f2b(sp2f(acc));
    }
}

// ---------- aggregation (bf16 gathers, fp32 accum, bf16 out; 2-edge ILP unroll) ----------
__global__ __launch_bounds__(256) void k_agg(const float2* __restrict__ edata,
    const int* __restrict__ off, const short* __restrict__ tabb,
    const short* __restrict__ nnb, short* __restrict__ aggb)
{
    const float SC = (float)(TAB - 1) / 5.0f;
    int tid = threadIdx.x;
    int c = tid & 63, r = tid >> 6;
    int n = blockIdx.x * 4 + r;
    if (n >= N_NODES) return;
    int e0 = off[n], e1 = off[n + 1];
    float acc = 0.f;
    int e = e0;
    for (; e + 2 <= e1; e += 2){
        float2 ev0 = edata[e];
        float2 ev1 = edata[e + 1];
        int s0 = __float_as_int(ev0.y), s1 = __float_as_int(ev1.y);
        float x0 = ev0.x * SC; int i00 = min((int)x0, TAB - 2); float f0 = x0 - (float)i00;
        float x1 = ev1.x * SC; int i01 = min((int)x1, TAB - 2); float f1 = x1 - (float)i01;
        float w00 = b2f(tabb[i00 * 64 + c]);
        float w01 = b2f(tabb[i00 * 64 + 64 + c]);
        float n0  = b2f(nnb[s0 * 64 + c]);
        float w10 = b2f(tabb[i01 * 64 + c]);
        float w11 = b2f(tabb[i01 * 64 + 64 + c]);
        float n1  = b2f(nnb[s1 * 64 + c]);
        acc += n0 * (w00 + (w01 - w00) * f0);
        acc += n1 * (w10 + (w11 - w10) * f1);
    }
    if (e < e1){
        float2 ev = edata[e];
        int s = __float_as_int(ev.y);
        float x = ev.x * SC; int i0 = min((int)x, TAB - 2); float f = x - (float)i0;
        float w0 = b2f(tabb[i0 * 64 + c]);
        float w1 = b2f(tabb[i0 * 64 + 64 + c]);
        acc += b2f(nnb[s * 64 + c]) * (w0 + (w1 - w0) * f);
    }
    aggb[n * 64 + c] = f2b(acc);
}

// ---------- MFMA: new_node = node @ conv_w1  (64 rows/block) ----------
__global__ __launch_bounds__(256) void k_gemm64(const short* __restrict__ nodeb,
    const short* __restrict__ wt, short* __restrict__ outb)
{
    int tid = threadIdx.x, wave = tid >> 6, lane = tid & 63;
    int quad = lane >> 4, l16 = lane & 15;
    int row0 = blockIdx.x * 64;
    f32x4 acc[4] = {{0,0,0,0},{0,0,0,0},{0,0,0,0},{0,0,0,0}};
    #pragma unroll
    for (int kt = 0; kt < 2; ++kt){
        int k0 = kt * 32 + quad * 8;
        int rw = row0 + wave * 16 + l16;
        bf16x8 a = (rw < N_NODES) ? *(const bf16x8*)&nodeb[rw * 64 + k0] : (bf16x8){0,0,0,0,0,0,0,0};
        #pragma unroll
        for (int ct = 0; ct < 4; ++ct){
            bf16x8 b = *(const bf16x8*)&wt[(ct * 16 + l16) * 64 + k0];
            acc[ct] = MFMA16(a, b, acc[ct]);
        }
    }
    #pragma unroll
    for (int ct = 0; ct < 4; ++ct)
        #pragma unroll
        for (int reg = 0; reg < 4; ++reg){
            int row = row0 + wave * 16 + quad * 4 + reg;
            if (row < N_NODES) outb[row * 64 + (ct * 16 + l16)] = f2b(acc[ct][reg]);
        }
}

// ---------- MFMA update: node += sp2(agg@nl2+b2)@nl3 + b3 (32 rows/block) ----------
__global__ __launch_bounds__(256) void k_update(const short* __restrict__ aggb,
    const short* __restrict__ nl2t, const float* __restrict__ nl2b,
    const short* __restrict__ nl3t, const float* __restrict__ nl3b,
    float* __restrict__ node, short* __restrict__ nodeb)
{
    __shared__ short sT[32 * 80];
    int tid = threadIdx.x, wave = tid >> 6, lane = tid & 63;
    int quad = lane >> 4, l16 = lane & 15;
    int row0 = blockIdx.x * 32;
    int rt = wave >> 1;
    int ctb = (wave & 1) * 2;
    f32x4 acc[2] = {{0,0,0,0},{0,0,0,0}};
    #pragma unroll
    for (int kt = 0; kt < 2; ++kt){
        int k0 = kt * 32 + quad * 8;
        int rw = row0 + rt * 16 + l16;
        bf16x8 a = (rw < N_NODES) ? *(const bf16x8*)&aggb[rw * 64 + k0] : (bf16x8){0,0,0,0,0,0,0,0};
        #pragma unroll
        for (int i = 0; i < 2; ++i){
            bf16x8 b = *(const bf16x8*)&nl2t[((ctb + i) * 16 + l16) * 64 + k0];
            acc[i] = MFMA16(a, b, acc[i]);
        }
    }
    #pragma unroll
    for (int i = 0; i < 2; ++i)
        #pragma unroll
        for (int reg = 0; reg < 4; ++reg){
            int rl = rt * 16 + quad * 4 + reg;
            int col = (ctb + i) * 16 + l16;
            sT[rl * 80 + col] = f2b(sp2f(acc[i][reg] + nl2b[col]));
        }
    __syncthreads();
    f32x4 acc2[2] = {{0,0,0,0},{0,0,0,0}};
    #pragma unroll
    for (int kt = 0; kt < 2; ++kt){
        int k0 = kt * 32 + quad * 8;
        bf16x8 a = *(const bf16x8*)&sT[(rt * 16 + l16) * 80 + k0];
        #pragma unroll
        for (int i = 0; i < 2; ++i){
            bf16x8 b = *(const bf16x8*)&nl3t[((ctb + i) * 16 + l16) * 64 + k0];
            acc2[i] = MFMA16(a, b, acc2[i]);
        }
    }
    #pragma unroll
    for (int i = 0; i < 2; ++i)
        #pragma unroll
        for (int reg = 0; reg < 4; ++reg){
            int row = row0 + rt * 16 + quad * 4 + reg;
            int col = (ctb + i) * 16 + l16;
            if (row < N_NODES){
                float v = node[row * 64 + col] + acc2[i][reg] + nl3b[col];
                node[row * 64 + col] = v;
                nodeb[row * 64 + col] = f2b(v);
            }
        }
}

// ---------- readout stage 1: atom = ssp(node@d1+b1), bf16 out (32 rows/block) ----------
__global__ __launch_bounds__(256) void k_r1(const short* __restrict__ nodeb,
    const short* __restrict__ d1t, const float* __restrict__ d1b,
    short* __restrict__ atomb)
{
    int tid = threadIdx.x, wave = tid >> 6, lane = tid & 63;
    int quad = lane >> 4, l16 = lane & 15;
    int row0 = blockIdx.x * 32;
    f32x4 acc[2][4] = {{{0,0,0,0},{0,0,0,0},{0,0,0,0},{0,0,0,0}},
                       {{0,0,0,0},{0,0,0,0},{0,0,0,0},{0,0,0,0}}};
    #pragma unroll
    for (int kt = 0; kt < 2; ++kt){
        int k0 = kt * 32 + quad * 8;
        bf16x8 a[2];
        #pragma unroll
        for (int rt = 0; rt < 2; ++rt){
            int rw = row0 + rt * 16 + l16;
            a[rt] = (rw < N_NODES) ? *(const bf16x8*)&nodeb[rw * 64 + k0] : (bf16x8){0,0,0,0,0,0,0,0};
        }
        #pragma unroll
        for (int ct = 0; ct < 4; ++ct){
            int n = wave * 64 + ct * 16 + l16;
            bf16x8 b = *(const bf16x8*)&d1t[n * 64 + k0];
            #pragma unroll
            for (int rt = 0; rt < 2; ++rt) acc[rt][ct] = MFMA16(a[rt], b, acc[rt][ct]);
        }
    }
    #pragma unroll
    for (int rt = 0; rt < 2; ++rt)
        #pragma unroll
        for (int ct = 0; ct < 4; ++ct){
            int col = wave * 64 + ct * 16 + l16;
            float bb = d1b[col];
            #pragma unroll
            for (int reg = 0; reg < 4; ++reg){
                int row = row0 + rt * 16 + quad * 4 + reg;
                if (row < N_NODES) atomb[row * HID + col] = f2b(sspf(acc[rt][ct][reg] + bb));
            }
        }
}

// ---------- readout stage 2: res = atom@d2+b2; pool to gacc; resb = bf16(relu(res)) ----------
__global__ __launch_bounds__(256) void k_r2(const short* __restrict__ atomb,
    const short* __restrict__ d2t, const float* __restrict__ d2b_,
    const int* __restrict__ gid, float* __restrict__ gacc, short* __restrict__ resb)
{
    __shared__ float sres[32 * 260];
    int tid = threadIdx.x, wave = tid >> 6, lane = tid & 63;
    int quad = lane >> 4, l16 = lane & 15;
    int row0 = blockIdx.x * 32;
    f32x4 acc[2][4] = {{{0,0,0,0},{0,0,0,0},{0,0,0,0},{0,0,0,0}},
                       {{0,0,0,0},{0,0,0,0},{0,0,0,0},{0,0,0,0}}};
    for (int kt = 0; kt < 8; ++kt){
        int k0 = kt * 32 + quad * 8;
        bf16x8 a[2];
        #pragma unroll
        for (int rt = 0; rt < 2; ++rt){
            int rw = row0 + rt * 16 + l16;
            a[rt] = (rw < N_NODES) ? *(const bf16x8*)&atomb[rw * HID + k0] : (bf16x8){0,0,0,0,0,0,0,0};
        }
        #pragma unroll
        for (int ct = 0; ct < 4; ++ct){
            int n = wave * 64 + ct * 16 + l16;
            bf16x8 b = *(const bf16x8*)&d2t[n * HID + k0];
            #pragma unroll
            for (int rt = 0; rt < 2; ++rt) acc[rt][ct] = MFMA16(a[rt], b, acc[rt][ct]);
        }
    }
    #pragma unroll
    for (int rt = 0; rt < 2; ++rt)
        #pragma unroll
        for (int ct = 0; ct < 4; ++ct){
            int col = wave * 64 + ct * 16 + l16;
            float bb = d2b_[col];
            #pragma unroll
            for (int reg = 0; reg < 4; ++reg){
                int rl = rt * 16 + quad * 4 + reg;
                sres[rl * 260 + col] = acc[rt][ct][reg] + bb;
            }
        }
    __syncthreads();
    float run = 0.f; int cur = -1;
    for (int r = 0; r < 32; ++r){
        int n = row0 + r;
        if (n >= N_NODES) break;
        float v = sres[r * 260 + tid];
        int g = gid[n];
        if (g != cur){
            if (cur >= 0) atomicAdd(&gacc[cur * HID + tid], run);
            run = 0.f; cur = g;
        }
        run += v;
        resb[n * HID + tid] = f2b(fmaxf(v, 0.f));
    }
    if (cur >= 0) atomicAdd(&gacc[cur * HID + tid], run);
}

// ---------- readout stage 3: atoms_preds = resb@ac + b ----------
__global__ __launch_bounds__(256) void k_r3(const short* __restrict__ resb,
    const short* __restrict__ act, const float* __restrict__ acb,
    float* __restrict__ out_atoms)
{
    int tid = threadIdx.x, wave = tid >> 6, lane = tid & 63;
    int quad = lane >> 4, l16 = lane & 15;
    int row0 = blockIdx.x * 64;
    f32x4 acc[7] = {{0,0,0,0},{0,0,0,0},{0,0,0,0},{0,0,0,0},{0,0,0,0},{0,0,0,0},{0,0,0,0}};
    for (int kt = 0; kt < 8; ++kt){
        int k0 = kt * 32 + quad * 8;
        int rw = row0 + wave * 16 + l16;
        bf16x8 a = (rw < N_NODES) ? *(const bf16x8*)&resb[rw * HID + k0] : (bf16x8){0,0,0,0,0,0,0,0};
        #pragma unroll
        for (int ct = 0; ct < 7; ++ct){
            bf16x8 b = *(const bf16x8*)&act[(ct * 16 + l16) * HID + k0];
            acc[ct] = MFMA16(a, b, acc[ct]);
        }
    }
    #pragma unroll
    for (int ct = 0; ct < 7; ++ct){
        int col = ct * 16 + l16;
        if (col >= ACT_DIM) continue;
        float bb = acb[col];
        #pragma unroll
        for (int reg = 0; reg < 4; ++reg){
            int row = row0 + wave * 16 + quad * 4 + reg;
            if (row < N_NODES) out_atoms[row * ACT_DIM + col] = acc[ct][reg] + bb;
        }
    }
}

// ---------- MFMA classifier: cls = emb_g @ cls_w + b (32 rows x 256 cols / block) ----------
__global__ __launch_bounds__(256) void k_cls2(const short* __restrict__ gclsb,
    const short* __restrict__ clswt, const float* __restrict__ clsb,
    float* __restrict__ out_cls)
{
    int tid = threadIdx.x, wave = tid >> 6, lane = tid & 63;
    int quad = lane >> 4, l16 = lane & 15;
    int row0 = blockIdx.x * 32;
    int colbase = blockIdx.y * 256 + wave * 64;
    f32x4 acc[2][4] = {{{0,0,0,0},{0,0,0,0},{0,0,0,0},{0,0,0,0}},
                       {{0,0,0,0},{0,0,0,0},{0,0,0,0},{0,0,0,0}}};
    for (int kt = 0; kt < 8; ++kt){
        int k0 = kt * 32 + quad * 8;
        bf16x8 a[2];
        #pragma unroll
        for (int rt = 0; rt < 2; ++rt){
            int rw = row0 + rt * 16 + l16;
            a[rt] = (rw < N_GRAPHS) ? *(const bf16x8*)&gclsb[rw * HID + k0] : (bf16x8){0,0,0,0,0,0,0,0};
        }
        #pragma unroll
        for (int ct = 0; ct < 4; ++ct){
            bf16x8 b = *(const bf16x8*)&clswt[(colbase + ct * 16 + l16) * HID + k0];
            #pragma unroll
            for (int rt = 0; rt < 2; ++rt) acc[rt][ct] = MFMA16(a[rt], b, acc[rt][ct]);
        }
    }
    #pragma unroll
    for (int rt = 0; rt < 2; ++rt)
        #pragma unroll
        for (int ct = 0; ct < 4; ++ct){
            int col = colbase + ct * 16 + l16;
            if (col >= CLS_DIM) continue;
            float bb = clsb[col];
            #pragma unroll
            for (int reg = 0; reg < 4; ++reg){
                int row = row0 + rt * 16 + quad * 4 + reg;
                if (row < N_GRAPHS) out_cls[row * CLS_DIM + col] = acc[rt][ct][reg] + bb;
            }
        }
}

extern "C" void kernel_launch(void* const* d_in, const int* in_sizes, int n_in,
                              void* d_out, int out_size, void* d_ws, size_t ws_size,
                              hipStream_t stream)
{
    const int*   node_types = (const int*)d_in[0];
    const int*   edge_src   = (const int*)d_in[1];
    const int*   edge_dst   = (const int*)d_in[2];
    const int*   graph_ids  = (const int*)d_in[3];
    const float* distance   = (const float*)d_in[4];
    const float* emb        = (const float*)d_in[5];
    const float* conv_w1    = (const float*)d_in[6];
    const float* cf1_w      = (const float*)d_in[7];
    const float* cf1_b      = (const float*)d_in[8];
    const float* cf2_w      = (const float*)d_in[9];
    const float* cf2_b      = (const float*)d_in[10];
    const float* nl2_w      = (const float*)d_in[11];
    const float* nl2_b      = (const float*)d_in[12];
    const float* nl3_w      = (const float*)d_in[13];
    const float* nl3_b      = (const float*)d_in[14];
    const float* d1_w       = (const float*)d_in[15];
    const float* d1_b       = (const float*)d_in[16];
    const float* d2_w       = (const float*)d_in[17];
    const float* d2_b       = (const float*)d_in[18];
    const float* cls_w      = (const float*)d_in[19];
    const float* cls_b      = (const float*)d_in[20];
    const float* ac_w       = (const float*)d_in[21];
    const float* ac_b       = (const float*)d_in[22];

    // ---- workspace layout (all 16B-aligned; ~67 MB total) ----
    float*  node   = (float*)d_ws;                 // 3,200,000 f
    float*  gacc   = node + 3200000;               // 128,000 f
    float*  counts = gacc + 128000;                // 512 f
    float2* edata  = (float2*)(counts + 512);      // 800,000 f2
    int*    off    = (int*)(edata + 800000);       // 50,001 i
    int*    cursor = off + 50001;                  // 50,003 i (pad for align)
    short*  nodeb  = (short*)(cursor + 50003);     // 3,200,000
    short*  nnb    = nodeb + 3200000;              // 3,200,000
    short*  aggb   = nnb + 3200000;                // 3,200,000
    short*  atomb  = aggb + 3200000;               // 12,800,000
    short*  resb   = atomb;                        // ALIAS: safe — k_r2 block reads its
                                                   // atom rows before writing resb rows
    short*  tabb   = atomb + 12800000;             // 131,072
    short*  cw1t   = tabb + 131072;                // 12,288
    short*  n2t    = cw1t + 12288;                 // 12,288
    short*  n3t    = n2t + 12288;                  // 12,288
    short*  d1t    = n3t + 12288;                  // 16,384
    short*  d2t    = d1t + 16384;                  // 65,536
    short*  act    = d2t + 65536;                  // 28,672
    short*  clswt  = act + 28672;                  // 524,288 (2048x256)
    short*  gclsb  = clswt + 524288;               // 128,000
    float*  out    = (float*)d_out;

    (void)hipMemsetAsync(gacc, 0, (128000 + 512) * sizeof(float), stream);
    (void)hipMemsetAsync(off, 0, (N_NODES + 1) * sizeof(int), stream);

    k_t64<<<dim3(16, 9), 256, 0, stream>>>(conv_w1, nl2_w, nl3_w, cw1t, n2t, n3t);
    k_tbig<<<dim3(256, 3), 256, 0, stream>>>(d1_w, d2_w, ac_w, d1t, d2t, act);
    k_tcls<<<2048, 256, 0, stream>>>(cls_w, clswt);

    k_embed<<<(N_NODES * DIM + 255) / 256, 256, 0, stream>>>(node_types, emb, node, nodeb);
    k_counts<<<(N_NODES + 255) / 256, 256, 0, stream>>>(graph_ids, counts);
    k_hist<<<(N_EDGES + 255) / 256, 256, 0, stream>>>(edge_dst, off);
    k_scan<<<1, 1024, 0, stream>>>(off, cursor);
    k_scatter<<<(N_EDGES + 255) / 256, 256, 0, stream>>>(edge_src, edge_dst, distance,
                                                         cursor, edata);

    for (int i = 0; i < N_CONV; ++i){
        k_gemm64<<<(N_NODES + 63) / 64, 256, 0, stream>>>(nodeb, cw1t + i * 4096, nnb);
        k_table<<<TAB / 4, 256, 0, stream>>>(cf1_w + i * RBF_DIM * DIM, cf1_b + i * DIM,
                                             cf2_w + i * DIM * DIM, cf2_b + i * DIM, tabb);
        k_agg<<<(N_NODES + 3) / 4, 256, 0, stream>>>(edata, off, tabb, nnb, aggb);
        k_update<<<(N_NODES + 31) / 32, 256, 0, stream>>>(aggb,
            n2t + i * 4096, nl2_b + i * DIM, n3t + i * 4096, nl3_b + i * DIM, node, nodeb);
    }

    k_r1<<<(N_NODES + 31) / 32, 256, 0, stream>>>(nodeb, d1t, d1_b, atomb);
    k_r2<<<(N_NODES + 31) / 32, 256, 0, stream>>>(atomb, d2t, d2_b, graph_ids, gacc, resb);
    k_r3<<<(N_NODES + 63) / 64, 256, 0, stream>>>(resb, act, ac_b, out);
    k_embg<<<(N_GRAPHS * HID + 255) / 256, 256, 0, stream>>>(gacc, counts, gclsb);
    k_cls2<<<dim3((N_GRAPHS + 31) / 32, (CLS_DIM + 255) / 256), 256, 0, stream>>>(
        gclsb, clswt, cls_b, out + N_NODES * ACT_DIM);
}

// Round 7
// 634.441 us; speedup vs baseline: 3.1400x; 1.1451x over previous
//
#include <hip/hip_runtime.h>
#include <math.h>

#define N_NODES 50000
#define N_EDGES 800000
#define N_GRAPHS 500
#define DIM 64
#define RBF_DIM 5
#define N_CONV 3
#define CLS_DIM 2000
#define ACT_DIM 100
#define HID 256
#define TAB 2048
#define SCAN_B 196          // ceil(50001/256)

typedef __attribute__((ext_vector_type(8))) short bf16x8;
typedef __attribute__((ext_vector_type(4))) float f32x4;
#define MFMA16(a,b,c) __builtin_amdgcn_mfma_f32_16x16x32_bf16(a,b,c,0,0,0)

__device__ __forceinline__ float sp2f(float x){
    float y = 0.5f * x;
    return 2.0f * (fmaxf(y, 0.0f) + log1pf(__expf(-fabsf(y))));
}
__device__ __forceinline__ float sspf(float x){
    return fmaxf(x, 0.0f) + log1pf(__expf(-fabsf(x))) - 0.69314718055994531f;
}
__device__ __forceinline__ short f2b(float x){
    union { float f; unsigned u; } v; v.f = x;
    unsigned r = v.u + 0x7FFFu + ((v.u >> 16) & 1u);
    return (short)(r >> 16);
}
__device__ __forceinline__ float b2f(short x){
    union { unsigned u; float f; } v; v.u = ((unsigned)(unsigned short)x) << 16;
    return v.f;
}

// ---------- fused: embed gather + graph counts + dst histogram ----------
__global__ void k_embed(const int* __restrict__ types, const float* __restrict__ emb,
                        float* __restrict__ node, short* __restrict__ nodeb,
                        const int* __restrict__ gid, float* __restrict__ counts,
                        const int* __restrict__ edst, int* __restrict__ off){
    int i = blockIdx.x * 256 + threadIdx.x;
    if (i < N_NODES * DIM){
        float v = emb[types[i >> 6] * DIM + (i & 63)];
        node[i] = v; nodeb[i] = f2b(v);
    }
    if (i < N_EDGES) atomicAdd(&off[edst[i] + 1], 1);
    if (i < N_NODES) atomicAdd(&counts[gid[i]], 1.0f);
}

// ---------- blocked scan: s1 (block sums) -> s2 (scan of sums) -> s3 (final) ----------
__global__ __launch_bounds__(256) void k_s1(const int* __restrict__ off, int* __restrict__ bsum){
    __shared__ int s[256];
    int tid = threadIdx.x;
    int idx = blockIdx.x * 256 + tid;
    s[tid] = (idx <= N_NODES) ? off[idx] : 0;
    __syncthreads();
    for (int d = 128; d > 0; d >>= 1){
        if (tid < d) s[tid] += s[tid + d];
        __syncthreads();
    }
    if (tid == 0) bsum[blockIdx.x] = s[0];
}

__global__ __launch_bounds__(256) void k_s2(const int* __restrict__ bsum, int* __restrict__ bpref){
    __shared__ int s[256];
    int tid = threadIdx.x;
    s[tid] = (tid < SCAN_B) ? bsum[tid] : 0;
    __syncthreads();
    for (int d = 1; d < 256; d <<= 1){
        int t = (tid >= d) ? s[tid - d] : 0;
        __syncthreads();
        s[tid] += t;
        __syncthreads();
    }
    bpref[tid] = (tid > 0) ? s[tid - 1] : 0;     // exclusive prefix of block sums
}

__global__ __launch_bounds__(256) void k_s3(const int* __restrict__ bpref,
                                            int* __restrict__ off, int* __restrict__ cursor){
    __shared__ int s[256];
    int tid = threadIdx.x;
    int idx = blockIdx.x * 256 + tid;
    int x = (idx <= N_NODES) ? off[idx] : 0;
    s[tid] = x;
    __syncthreads();
    for (int d = 1; d < 256; d <<= 1){
        int t = (tid >= d) ? s[tid - d] : 0;
        __syncthreads();
        s[tid] += t;
        __syncthreads();
    }
    if (idx <= N_NODES){
        int val = s[tid] + bpref[blockIdx.x];
        off[idx] = val; cursor[idx] = val;
    }
}

__global__ void k_scatter(const int* __restrict__ esrc, const int* __restrict__ edst,
                          const float* __restrict__ dist, int* __restrict__ cursor,
                          float2* __restrict__ edata){
    int e = blockIdx.x * 256 + threadIdx.x;
    if (e >= N_EDGES) return;
    int pos = atomicAdd(&cursor[edst[e]], 1);
    edata[pos] = make_float2(dist[e], __int_as_float(esrc[e]));
}

// ---------- fused weight transposes (all 7 matrices, one launch, 2624 blocks) ----------
__global__ void k_tw(const float* __restrict__ cw, const float* __restrict__ n2,
                     const float* __restrict__ n3, const float* __restrict__ d1w,
                     const float* __restrict__ d2w, const float* __restrict__ acw,
                     const float* __restrict__ clsw,
                     short* __restrict__ cwt, short* __restrict__ n2t, short* __restrict__ n3t,
                     short* __restrict__ d1t, short* __restrict__ d2t, short* __restrict__ act,
                     short* __restrict__ clswt){
    int b = blockIdx.x, tid = threadIdx.x;
    if (b < 144){                                  // 9x 64x64
        int i = b * 256 + tid;
        int y = i >> 12, j = i & 4095;
        int which = y / 3, layer = y % 3;
        const float* src = (which == 0 ? cw : which == 1 ? n2 : n3) + layer * 4096;
        short* dst = (which == 0 ? cwt : which == 1 ? n2t : n3t) + layer * 4096;
        int k = j >> 6, n = j & 63;
        dst[n * 64 + k] = f2b(src[k * 64 + n]);
    } else if (b < 208){                           // d1 64x256
        int i = (b - 144) * 256 + tid;
        int k = i >> 8, n = i & 255;
        d1t[n * 64 + k] = f2b(d1w[k * 256 + n]);
    } else if (b < 464){                           // d2 256x256
        int i = (b - 208) * 256 + tid;
        int k = i >> 8, n = i & 255;
        d2t[n * 256 + k] = f2b(d2w[k * 256 + n]);
    } else if (b < 576){                           // ac 256x100 -> pad 112
        int i = (b - 464) * 256 + tid;
        int n = i >> 8, k = i & 255;
        act[n * 256 + k] = f2b(n < ACT_DIM ? acw[k * ACT_DIM + n] : 0.f);
    } else {                                       // cls 256x2000 -> pad 2048
        int i = (b - 576) * 256 + tid;
        int k = i >> 11, n = i & 2047;
        clswt[n * 256 + k] = f2b(n < CLS_DIM ? clsw[k * CLS_DIM + n] : 0.f);
    }
}

// emb_g = gacc / counts -> bf16 [500][256]
__global__ void k_embg(const float* __restrict__ gacc, const float* __restrict__ counts,
                       short* __restrict__ gclsb){
    int i = blockIdx.x * 256 + threadIdx.x;
    if (i < N_GRAPHS * HID){
        int g = i >> 8;
        gclsb[i] = f2b(gacc[i] / fmaxf(counts[g], 1.0f));
    }
}

// ---------- all 3 layers' filter tables in one launch: grid (TAB/4, 3) ----------
__global__ __launch_bounds__(256) void k_table3(const float* __restrict__ cf1w_all,
    const float* __restrict__ cf1b_all, const float* __restrict__ cf2w_all,
    const float* __restrict__ cf2b_all, short* __restrict__ tabb_all)
{
    int L = blockIdx.y;
    const float* cf1w = cf1w_all + L * RBF_DIM * DIM;
    const float* cf1b = cf1b_all + L * DIM;
    const float* cf2w = cf2w_all + L * DIM * DIM;
    const float* cf2b = cf2b_all + L * DIM;
    short* tabb = tabb_all + L * TAB * 64;
    __shared__ float s_cf1[RBF_DIM * 64];
    __shared__ float s_cf1b[64], s_cf2b[64];
    __shared__ float s_cf2[64 * 64];
    __shared__ float s_h1[4 * 64];
    int tid = threadIdx.x;
    int c = tid & 63, g = tid >> 6;
    for (int i = tid; i < 64 * 64; i += 256) s_cf2[i] = cf2w[i];
    for (int i = tid; i < RBF_DIM * 64; i += 256) s_cf1[i] = cf1w[i];
    if (tid < 64){ s_cf1b[tid] = cf1b[tid]; s_cf2b[tid] = cf2b[tid]; }
    __syncthreads();
    int entry = blockIdx.x * 4 + g;
    float d = (float)entry * (5.0f / (float)(TAB - 1));
    {
        float acc = s_cf1b[c];
        #pragma unroll
        for (int j = 0; j < RBF_DIM; ++j){
            float t = d - 1.25f * (float)j;
            acc += __expf(-0.8f * t * t) * s_cf1[j * 64 + c];
        }
        s_h1[g * 64 + c] = sp2f(acc);
    }
    __syncthreads();
    {
        float acc = s_cf2b[c];
        #pragma unroll 8
        for (int k = 0; k < 64; ++k) acc += s_h1[g * 64 + k] * s_cf2[k * 64 + c];
        tabb[entry * 64 + c] = f2b(sp2f(acc));
    }
}

// ---------- aggregation (bf16 gathers, fp32 accum, bf16 out; 2-edge ILP unroll) ----------
__global__ __launch_bounds__(256) void k_agg(const float2* __restrict__ edata,
    const int* __restrict__ off, const short* __restrict__ tabb,
    const short* __restrict__ nnb, short* __restrict__ aggb)
{
    const float SC = (float)(TAB - 1) / 5.0f;
    int tid = threadIdx.x;
    int c = tid & 63, r = tid >> 6;
    int n = blockIdx.x * 4 + r;
    if (n >= N_NODES) return;
    int e0 = off[n], e1 = off[n + 1];
    float acc = 0.f;
    int e = e0;
    for (; e + 2 <= e1; e += 2){
        float2 ev0 = edata[e];
        float2 ev1 = edata[e + 1];
        int s0 = __float_as_int(ev0.y), s1 = __float_as_int(ev1.y);
        float x0 = ev0.x * SC; int i00 = min((int)x0, TAB - 2); float f0 = x0 - (float)i00;
        float x1 = ev1.x * SC; int i01 = min((int)x1, TAB - 2); float f1 = x1 - (float)i01;
        float w00 = b2f(tabb[i00 * 64 + c]);
        float w01 = b2f(tabb[i00 * 64 + 64 + c]);
        float n0  = b2f(nnb[s0 * 64 + c]);
        float w10 = b2f(tabb[i01 * 64 + c]);
        float w11 = b2f(tabb[i01 * 64 + 64 + c]);
        float n1  = b2f(nnb[s1 * 64 + c]);
        acc += n0 * (w00 + (w01 - w00) * f0);
        acc += n1 * (w10 + (w11 - w10) * f1);
    }
    if (e < e1){
        float2 ev = edata[e];
        int s = __float_as_int(ev.y);
        float x = ev.x * SC; int i0 = min((int)x, TAB - 2); float f = x - (float)i0;
        float w0 = b2f(tabb[i0 * 64 + c]);
        float w1 = b2f(tabb[i0 * 64 + 64 + c]);
        acc += b2f(nnb[s * 64 + c]) * (w0 + (w1 - w0) * f);
    }
    aggb[n * 64 + c] = f2b(acc);
}

// ---------- MFMA: new_node = node @ conv_w1  (64 rows/block) ----------
__global__ __launch_bounds__(256) void k_gemm64(const short* __restrict__ nodeb,
    const short* __restrict__ wt, short* __restrict__ outb)
{
    int tid = threadIdx.x, wave = tid >> 6, lane = tid & 63;
    int quad = lane >> 4, l16 = lane & 15;
    int row0 = blockIdx.x * 64;
    f32x4 acc[4] = {{0,0,0,0},{0,0,0,0},{0,0,0,0},{0,0,0,0}};
    #pragma unroll
    for (int kt = 0; kt < 2; ++kt){
        int k0 = kt * 32 + quad * 8;
        int rw = row0 + wave * 16 + l16;
        bf16x8 a = (rw < N_NODES) ? *(const bf16x8*)&nodeb[rw * 64 + k0] : (bf16x8){0,0,0,0,0,0,0,0};
        #pragma unroll
        for (int ct = 0; ct < 4; ++ct){
            bf16x8 b = *(const bf16x8*)&wt[(ct * 16 + l16) * 64 + k0];
            acc[ct] = MFMA16(a, b, acc[ct]);
        }
    }
    #pragma unroll
    for (int ct = 0; ct < 4; ++ct)
        #pragma unroll
        for (int reg = 0; reg < 4; ++reg){
            int row = row0 + wave * 16 + quad * 4 + reg;
            if (row < N_NODES) outb[row * 64 + (ct * 16 + l16)] = f2b(acc[ct][reg]);
        }
}

// ---------- MFMA update: node += sp2(agg@nl2+b2)@nl3 + b3 (32 rows/block) ----------
__global__ __launch_bounds__(256) void k_update(const short* __restrict__ aggb,
    const short* __restrict__ nl2t, const float* __restrict__ nl2b,
    const short* __restrict__ nl3t, const float* __restrict__ nl3b,
    float* __restrict__ node, short* __restrict__ nodeb)
{
    __shared__ short sT[32 * 80];
    int tid = threadIdx.x, wave = tid >> 6, lane = tid & 63;
    int quad = lane >> 4, l16 = lane & 15;
    int row0 = blockIdx.x * 32;
    int rt = wave >> 1;
    int ctb = (wave & 1) * 2;
    f32x4 acc[2] = {{0,0,0,0},{0,0,0,0}};
    #pragma unroll
    for (int kt = 0; kt < 2; ++kt){
        int k0 = kt * 32 + quad * 8;
        int rw = row0 + rt * 16 + l16;
        bf16x8 a = (rw < N_NODES) ? *(const bf16x8*)&aggb[rw * 64 + k0] : (bf16x8){0,0,0,0,0,0,0,0};
        #pragma unroll
        for (int i = 0; i < 2; ++i){
            bf16x8 b = *(const bf16x8*)&nl2t[((ctb + i) * 16 + l16) * 64 + k0];
            acc[i] = MFMA16(a, b, acc[i]);
        }
    }
    #pragma unroll
    for (int i = 0; i < 2; ++i)
        #pragma unroll
        for (int reg = 0; reg < 4; ++reg){
            int rl = rt * 16 + quad * 4 + reg;
            int col = (ctb + i) * 16 + l16;
            sT[rl * 80 + col] = f2b(sp2f(acc[i][reg] + nl2b[col]));
        }
    __syncthreads();
    f32x4 acc2[2] = {{0,0,0,0},{0,0,0,0}};
    #pragma unroll
    for (int kt = 0; kt < 2; ++kt){
        int k0 = kt * 32 + quad * 8;
        bf16x8 a = *(const bf16x8*)&sT[(rt * 16 + l16) * 80 + k0];
        #pragma unroll
        for (int i = 0; i < 2; ++i){
            bf16x8 b = *(const bf16x8*)&nl3t[((ctb + i) * 16 + l16) * 64 + k0];
            acc2[i] = MFMA16(a, b, acc2[i]);
        }
    }
    #pragma unroll
    for (int i = 0; i < 2; ++i)
        #pragma unroll
        for (int reg = 0; reg < 4; ++reg){
            int row = row0 + rt * 16 + quad * 4 + reg;
            int col = (ctb + i) * 16 + l16;
            if (row < N_NODES){
                float v = node[row * 64 + col] + acc2[i][reg] + nl3b[col];
                node[row * 64 + col] = v;
                nodeb[row * 64 + col] = f2b(v);
            }
        }
}

// ---------- readout stage 1: atom = ssp(node@d1+b1), bf16 out (32 rows/block) ----------
__global__ __launch_bounds__(256) void k_r1(const short* __restrict__ nodeb,
    const short* __restrict__ d1t, const float* __restrict__ d1b,
    short* __restrict__ atomb)
{
    int tid = threadIdx.x, wave = tid >> 6, lane = tid & 63;
    int quad = lane >> 4, l16 = lane & 15;
    int row0 = blockIdx.x * 32;
    f32x4 acc[2][4] = {{{0,0,0,0},{0,0,0,0},{0,0,0,0},{0,0,0,0}},
                       {{0,0,0,0},{0,0,0,0},{0,0,0,0},{0,0,0,0}}};
    #pragma unroll
    for (int kt = 0; kt < 2; ++kt){
        int k0 = kt * 32 + quad * 8;
        bf16x8 a[2];
        #pragma unroll
        for (int rt = 0; rt < 2; ++rt){
            int rw = row0 + rt * 16 + l16;
            a[rt] = (rw < N_NODES) ? *(const bf16x8*)&nodeb[rw * 64 + k0] : (bf16x8){0,0,0,0,0,0,0,0};
        }
        #pragma unroll
        for (int ct = 0; ct < 4; ++ct){
            int n = wave * 64 + ct * 16 + l16;
            bf16x8 b = *(const bf16x8*)&d1t[n * 64 + k0];
            #pragma unroll
            for (int rt = 0; rt < 2; ++rt) acc[rt][ct] = MFMA16(a[rt], b, acc[rt][ct]);
        }
    }
    #pragma unroll
    for (int rt = 0; rt < 2; ++rt)
        #pragma unroll
        for (int ct = 0; ct < 4; ++ct){
            int col = wave * 64 + ct * 16 + l16;
            float bb = d1b[col];
            #pragma unroll
            for (int reg = 0; reg < 4; ++reg){
                int row = row0 + rt * 16 + quad * 4 + reg;
                if (row < N_NODES) atomb[row * HID + col] = f2b(sspf(acc[rt][ct][reg] + bb));
            }
        }
}

// ---------- readout stage 2: res = atom@d2+b2; pool to gacc; resb = bf16(relu(res)) ----------
__global__ __launch_bounds__(256) void k_r2(const short* __restrict__ atomb,
    const short* __restrict__ d2t, const float* __restrict__ d2b_,
    const int* __restrict__ gid, float* __restrict__ gacc, short* __restrict__ resb)
{
    __shared__ float sres[32 * 260];
    int tid = threadIdx.x, wave = tid >> 6, lane = tid & 63;
    int quad = lane >> 4, l16 = lane & 15;
    int row0 = blockIdx.x * 32;
    f32x4 acc[2][4] = {{{0,0,0,0},{0,0,0,0},{0,0,0,0},{0,0,0,0}},
                       {{0,0,0,0},{0,0,0,0},{0,0,0,0},{0,0,0,0}}};
    for (int kt = 0; kt < 8; ++kt){
        int k0 = kt * 32 + quad * 8;
        bf16x8 a[2];
        #pragma unroll
        for (int rt = 0; rt < 2; ++rt){
            int rw = row0 + rt * 16 + l16;
            a[rt] = (rw < N_NODES) ? *(const bf16x8*)&atomb[rw * HID + k0] : (bf16x8){0,0,0,0,0,0,0,0};
        }
        #pragma unroll
        for (int ct = 0; ct < 4; ++ct){
            int n = wave * 64 + ct * 16 + l16;
            bf16x8 b = *(const bf16x8*)&d2t[n * HID + k0];
            #pragma unroll
            for (int rt = 0; rt < 2; ++rt) acc[rt][ct] = MFMA16(a[rt], b, acc[rt][ct]);
        }
    }
    #pragma unroll
    for (int rt = 0; rt < 2; ++rt)
        #pragma unroll
        for (int ct = 0; ct < 4; ++ct){
            int col = wave * 64 + ct * 16 + l16;
            float bb = d2b_[col];
            #pragma unroll
            for (int reg = 0; reg < 4; ++reg){
                int rl = rt * 16 + quad * 4 + reg;
                sres[rl * 260 + col] = acc[rt][ct][reg] + bb;
            }
        }
    __syncthreads();
    float run = 0.f; int cur = -1;
    for (int r = 0; r < 32; ++r){
        int n = row0 + r;
        if (n >= N_NODES) break;
        float v = sres[r * 260 + tid];
        int g = gid[n];
        if (g != cur){
            if (cur >= 0) atomicAdd(&gacc[cur * HID + tid], run);
            run = 0.f; cur = g;
        }
        run += v;
        resb[n * HID + tid] = f2b(fmaxf(v, 0.f));
    }
    if (cur >= 0) atomicAdd(&gacc[cur * HID + tid], run);
}

// ---------- readout stage 3: atoms_preds = resb@ac + b ----------
__global__ __launch_bounds__(256) void k_r3(const short* __restrict__ resb,
    const short* __restrict__ act, const float* __restrict__ acb,
    float* __restrict__ out_atoms)
{
    int tid = threadIdx.x, wave = tid >> 6, lane = tid & 63;
    int quad = lane >> 4, l16 = lane & 15;
    int row0 = blockIdx.x * 64;
    f32x4 acc[7] = {{0,0,0,0},{0,0,0,0},{0,0,0,0},{0,0,0,0},{0,0,0,0},{0,0,0,0},{0,0,0,0}};
    for (int kt = 0; kt < 8; ++kt){
        int k0 = kt * 32 + quad * 8;
        int rw = row0 + wave * 16 + l16;
        bf16x8 a = (rw < N_NODES) ? *(const bf16x8*)&resb[rw * HID + k0] : (bf16x8){0,0,0,0,0,0,0,0};
        #pragma unroll
        for (int ct = 0; ct < 7; ++ct){
            bf16x8 b = *(const bf16x8*)&act[(ct * 16 + l16) * HID + k0];
            acc[ct] = MFMA16(a, b, acc[ct]);
        }
    }
    #pragma unroll
    for (int ct = 0; ct < 7; ++ct){
        int col = ct * 16 + l16;
        if (col >= ACT_DIM) continue;
        float bb = acb[col];
        #pragma unroll
        for (int reg = 0; reg < 4; ++reg){
            int row = row0 + wave * 16 + quad * 4 + reg;
            if (row < N_NODES) out_atoms[row * ACT_DIM + col] = acc[ct][reg] + bb;
        }
    }
}

// ---------- MFMA classifier ----------
__global__ __launch_bounds__(256) void k_cls2(const short* __restrict__ gclsb,
    const short* __restrict__ clswt, const float* __restrict__ clsb,
    float* __restrict__ out_cls)
{
    int tid = threadIdx.x, wave = tid >> 6, lane = tid & 63;
    int quad = lane >> 4, l16 = lane & 15;
    int row0 = blockIdx.x * 32;
    int colbase = blockIdx.y * 256 + wave * 64;
    f32x4 acc[2][4] = {{{0,0,0,0},{0,0,0,0},{0,0,0,0},{0,0,0,0}},
                       {{0,0,0,0},{0,0,0,0},{0,0,0,0},{0,0,0,0}}};
    for (int kt = 0; kt < 8; ++kt){
        int k0 = kt * 32 + quad * 8;
        bf16x8 a[2];
        #pragma unroll
        for (int rt = 0; rt < 2; ++rt){
            int rw = row0 + rt * 16 + l16;
            a[rt] = (rw < N_GRAPHS) ? *(const bf16x8*)&gclsb[rw * HID + k0] : (bf16x8){0,0,0,0,0,0,0,0};
        }
        #pragma unroll
        for (int ct = 0; ct < 4; ++ct){
            bf16x8 b = *(const bf16x8*)&clswt[(colbase + ct * 16 + l16) * HID + k0];
            #pragma unroll
            for (int rt = 0; rt < 2; ++rt) acc[rt][ct] = MFMA16(a[rt], b, acc[rt][ct]);
        }
    }
    #pragma unroll
    for (int rt = 0; rt < 2; ++rt)
        #pragma unroll
        for (int ct = 0; ct < 4; ++ct){
            int col = colbase + ct * 16 + l16;
            if (col >= CLS_DIM) continue;
            float bb = clsb[col];
            #pragma unroll
            for (int reg = 0; reg < 4; ++reg){
                int row = row0 + rt * 16 + quad * 4 + reg;
                if (row < N_GRAPHS) out_cls[row * CLS_DIM + col] = acc[rt][ct][reg] + bb;
            }
        }
}

extern "C" void kernel_launch(void* const* d_in, const int* in_sizes, int n_in,
                              void* d_out, int out_size, void* d_ws, size_t ws_size,
                              hipStream_t stream)
{
    const int*   node_types = (const int*)d_in[0];
    const int*   edge_src   = (const int*)d_in[1];
    const int*   edge_dst   = (const int*)d_in[2];
    const int*   graph_ids  = (const int*)d_in[3];
    const float* distance   = (const float*)d_in[4];
    const float* emb        = (const float*)d_in[5];
    const float* conv_w1    = (const float*)d_in[6];
    const float* cf1_w      = (const float*)d_in[7];
    const float* cf1_b      = (const float*)d_in[8];
    const float* cf2_w      = (const float*)d_in[9];
    const float* cf2_b      = (const float*)d_in[10];
    const float* nl2_w      = (const float*)d_in[11];
    const float* nl2_b      = (const float*)d_in[12];
    const float* nl3_w      = (const float*)d_in[13];
    const float* nl3_b      = (const float*)d_in[14];
    const float* d1_w       = (const float*)d_in[15];
    const float* d1_b       = (const float*)d_in[16];
    const float* d2_w       = (const float*)d_in[17];
    const float* d2_b       = (const float*)d_in[18];
    const float* cls_w      = (const float*)d_in[19];
    const float* cls_b      = (const float*)d_in[20];
    const float* ac_w       = (const float*)d_in[21];
    const float* ac_b       = (const float*)d_in[22];

    // ---- workspace layout (16B-aligned; ~68 MB) ----
    float*  node   = (float*)d_ws;                 // 3,200,000 f
    float*  gacc   = node + 3200000;               // 128,000 f
    float*  counts = gacc + 128000;                // 512 f
    float2* edata  = (float2*)(counts + 512);      // 800,000 f2
    int*    off    = (int*)(edata + 800000);       // 50,001 i
    int*    cursor = off + 50001;                  // 50,003 i (pad)
    int*    bsum   = cursor + 50003;               // 256 i
    int*    bpref  = bsum + 256;                   // 256 i
    short*  nodeb  = (short*)(bpref + 256);        // 3,200,000
    short*  nnb    = nodeb + 3200000;              // 3,200,000
    short*  aggb   = nnb + 3200000;                // 3,200,000
    short*  atomb  = aggb + 3200000;               // 12,800,000
    short*  resb   = atomb;                        // ALIAS: safe (see R4 note)
    short*  tabb   = atomb + 12800000;             // 3 * 131,072
    short*  cw1t   = tabb + 3 * 131072;            // 12,288
    short*  n2t    = cw1t + 12288;                 // 12,288
    short*  n3t    = n2t + 12288;                  // 12,288
    short*  d1t    = n3t + 12288;                  // 16,384
    short*  d2t    = d1t + 16384;                  // 65,536
    short*  act    = d2t + 65536;                  // 28,672
    short*  clswt  = act + 28672;                  // 524,288
    short*  gclsb  = clswt + 524288;               // 128,000
    float*  out    = (float*)d_out;

    (void)hipMemsetAsync(gacc, 0, (128000 + 512) * sizeof(float), stream);
    (void)hipMemsetAsync(off, 0, (N_NODES + 1) * sizeof(int), stream);

    k_tw<<<2624, 256, 0, stream>>>(conv_w1, nl2_w, nl3_w, d1_w, d2_w, ac_w, cls_w,
                                   cw1t, n2t, n3t, d1t, d2t, act, clswt);
    k_table3<<<dim3(TAB / 4, 3), 256, 0, stream>>>(cf1_w, cf1_b, cf2_w, cf2_b, tabb);

    k_embed<<<(N_NODES * DIM + 255) / 256, 256, 0, stream>>>(node_types, emb, node, nodeb,
                                                             graph_ids, counts, edge_dst, off);
    k_s1<<<SCAN_B, 256, 0, stream>>>(off, bsum);
    k_s2<<<1, 256, 0, stream>>>(bsum, bpref);
    k_s3<<<SCAN_B, 256, 0, stream>>>(bpref, off, cursor);
    k_scatter<<<(N_EDGES + 255) / 256, 256, 0, stream>>>(edge_src, edge_dst, distance,
                                                         cursor, edata);

    for (int i = 0; i < N_CONV; ++i){
        k_gemm64<<<(N_NODES + 63) / 64, 256, 0, stream>>>(nodeb, cw1t + i * 4096, nnb);
        k_agg<<<(N_NODES + 3) / 4, 256, 0, stream>>>(edata, off, tabb + i * TAB * 64, nnb, aggb);
        k_update<<<(N_NODES + 31) / 32, 256, 0, stream>>>(aggb,
            n2t + i * 4096, nl2_b + i * DIM, n3t + i * 4096, nl3_b + i * DIM, node, nodeb);
    }

    k_r1<<<(N_NODES + 31) / 32, 256, 0, stream>>>(nodeb, d1t, d1_b, atomb);
    k_r2<<<(N_NODES + 31) / 32, 256, 0, stream>>>(atomb, d2t, d2_b, graph_ids, gacc, resb);
    k_r3<<<(N_NODES + 63) / 64, 256, 0, stream>>>(resb, act, ac_b, out);
    k_embg<<<(N_GRAPHS * HID + 255) / 256, 256, 0, stream>>>(gacc, counts, gclsb);
    k_cls2<<<dim3((N_GRAPHS + 31) / 32, (CLS_DIM + 255) / 256), 256, 0, stream>>>(
        gclsb, clswt, cls_b, out + N_NODES * ACT_DIM);
}

// Round 8
// 532.115 us; speedup vs baseline: 3.7438x; 1.1923x over previous
//
#include <hip/hip_runtime.h>
#include <math.h>

#define N_NODES 50000
#define N_EDGES 800000
#define N_GRAPHS 500
#define DIM 64
#define RBF_DIM 5
#define N_CONV 3
#define CLS_DIM 2000
#define ACT_DIM 100
#define HID 256
#define TAB 2048
#define CAP 64            // max in-degree slot capacity (Poisson(16): P(>=64)~1e-55)

typedef __attribute__((ext_vector_type(8))) short bf16x8;
typedef __attribute__((ext_vector_type(4))) float f32x4;
#define MFMA16(a,b,c) __builtin_amdgcn_mfma_f32_16x16x32_bf16(a,b,c,0,0,0)

__device__ __forceinline__ float sp2f(float x){
    float y = 0.5f * x;
    return 2.0f * (fmaxf(y, 0.0f) + log1pf(__expf(-fabsf(y))));
}
__device__ __forceinline__ float sspf(float x){
    return fmaxf(x, 0.0f) + log1pf(__expf(-fabsf(x))) - 0.69314718055994531f;
}
__device__ __forceinline__ short f2b(float x){
    union { float f; unsigned u; } v; v.f = x;
    unsigned r = v.u + 0x7FFFu + ((v.u >> 16) & 1u);
    return (short)(r >> 16);
}
__device__ __forceinline__ float b2f(short x){
    union { unsigned u; float f; } v; v.u = ((unsigned)(unsigned short)x) << 16;
    return v.f;
}

// ---------- fused weight prep: 7 transposes + embW = emb @ conv_w1[0] ----------
__global__ void k_tw(const float* __restrict__ cw, const float* __restrict__ n2,
                     const float* __restrict__ n3, const float* __restrict__ d1w,
                     const float* __restrict__ d2w, const float* __restrict__ acw,
                     const float* __restrict__ clsw, const float* __restrict__ emb,
                     short* __restrict__ cwt, short* __restrict__ n2t, short* __restrict__ n3t,
                     short* __restrict__ d1t, short* __restrict__ d2t, short* __restrict__ act,
                     short* __restrict__ clswt, short* __restrict__ embw0b){
    int b = blockIdx.x, tid = threadIdx.x;
    if (b < 144){                                  // 9x 64x64
        int i = b * 256 + tid;
        int y = i >> 12, j = i & 4095;
        int which = y / 3, layer = y % 3;
        const float* src = (which == 0 ? cw : which == 1 ? n2 : n3) + layer * 4096;
        short* dst = (which == 0 ? cwt : which == 1 ? n2t : n3t) + layer * 4096;
        int k = j >> 6, n = j & 63;
        dst[n * 64 + k] = f2b(src[k * 64 + n]);
    } else if (b < 208){                           // d1 64x256
        int i = (b - 144) * 256 + tid;
        int k = i >> 8, n = i & 255;
        d1t[n * 64 + k] = f2b(d1w[k * 256 + n]);
    } else if (b < 464){                           // d2 256x256
        int i = (b - 208) * 256 + tid;
        int k = i >> 8, n = i & 255;
        d2t[n * 256 + k] = f2b(d2w[k * 256 + n]);
    } else if (b < 576){                           // ac 256x100 -> pad 112
        int i = (b - 464) * 256 + tid;
        int n = i >> 8, k = i & 255;
        act[n * 256 + k] = f2b(n < ACT_DIM ? acw[k * ACT_DIM + n] : 0.f);
    } else if (b < 2624){                          // cls 256x2000 -> pad 2048
        int i = (b - 576) * 256 + tid;
        int k = i >> 11, n = i & 2047;
        clswt[n * 256 + k] = f2b(n < CLS_DIM ? clsw[k * CLS_DIM + n] : 0.f);
    } else {                                       // embW0 = emb @ conv_w1[0]  (100x64)
        int i = (b - 2624) * 256 + tid;
        if (i < 100 * 64){
            int t = i >> 6, c = i & 63;
            float a = 0.f;
            #pragma unroll 8
            for (int k = 0; k < 64; ++k) a += emb[t * 64 + k] * cw[k * 64 + c];
            embw0b[i] = f2b(a);
        }
    }
}

// ---------- fused: embed gather + nnb(layer0) gather + graph counts ----------
__global__ void k_embed(const int* __restrict__ types, const float* __restrict__ emb,
                        const short* __restrict__ embw0b,
                        float* __restrict__ node, short* __restrict__ nodeb,
                        short* __restrict__ nnb,
                        const int* __restrict__ gid, float* __restrict__ counts){
    int i = blockIdx.x * 256 + threadIdx.x;
    if (i < N_NODES * DIM){
        int t = types[i >> 6], c = i & 63;
        float v = emb[t * 64 + c];
        node[i] = v; nodeb[i] = f2b(v);
        nnb[i] = embw0b[t * 64 + c];
    }
    if (i < N_NODES) atomicAdd(&counts[gid[i]], 1.0f);
}

// ---------- single-pass bucketed edge scatter (no hist/scan) ----------
__global__ void k_scatter2(const int* __restrict__ esrc, const int* __restrict__ edst,
                           const float* __restrict__ dist, int* __restrict__ cnt,
                           float2* __restrict__ edata2){
    int e = blockIdx.x * 256 + threadIdx.x;
    if (e >= N_EDGES) return;
    int d = edst[e];
    int pos = atomicAdd(&cnt[d], 1);
    if (pos < CAP) edata2[d * CAP + pos] = make_float2(dist[e], __int_as_float(esrc[e]));
}

// ---------- all 3 layers' filter tables ----------
__global__ __launch_bounds__(256) void k_table3(const float* __restrict__ cf1w_all,
    const float* __restrict__ cf1b_all, const float* __restrict__ cf2w_all,
    const float* __restrict__ cf2b_all, short* __restrict__ tabb_all)
{
    int L = blockIdx.y;
    const float* cf1w = cf1w_all + L * RBF_DIM * DIM;
    const float* cf1b = cf1b_all + L * DIM;
    const float* cf2w = cf2w_all + L * DIM * DIM;
    const float* cf2b = cf2b_all + L * DIM;
    short* tabb = tabb_all + L * TAB * 64;
    __shared__ float s_cf1[RBF_DIM * 64];
    __shared__ float s_cf1b[64], s_cf2b[64];
    __shared__ float s_cf2[64 * 64];
    __shared__ float s_h1[4 * 64];
    int tid = threadIdx.x;
    int c = tid & 63, g = tid >> 6;
    for (int i = tid; i < 64 * 64; i += 256) s_cf2[i] = cf2w[i];
    for (int i = tid; i < RBF_DIM * 64; i += 256) s_cf1[i] = cf1w[i];
    if (tid < 64){ s_cf1b[tid] = cf1b[tid]; s_cf2b[tid] = cf2b[tid]; }
    __syncthreads();
    int entry = blockIdx.x * 4 + g;
    float d = (float)entry * (5.0f / (float)(TAB - 1));
    {
        float acc = s_cf1b[c];
        #pragma unroll
        for (int j = 0; j < RBF_DIM; ++j){
            float t = d - 1.25f * (float)j;
            acc += __expf(-0.8f * t * t) * s_cf1[j * 64 + c];
        }
        s_h1[g * 64 + c] = sp2f(acc);
    }
    __syncthreads();
    {
        float acc = s_cf2b[c];
        #pragma unroll 8
        for (int k = 0; k < 64; ++k) acc += s_h1[g * 64 + k] * s_cf2[k * 64 + c];
        tabb[entry * 64 + c] = f2b(sp2f(acc));
    }
}

// pack adjacent table entries: tabp[t][c] = (eh[t][c], eh[t+1][c]) as one uint
__global__ void k_pack(const short* __restrict__ tabb_all, unsigned* __restrict__ tabp_all){
    int L = blockIdx.y;
    int i = blockIdx.x * 256 + threadIdx.x;
    if (i < (TAB - 1) * 64){
        int t = i >> 6, c = i & 63;
        unsigned lo = (unsigned short)tabb_all[L * TAB * 64 + t * 64 + c];
        unsigned hi = (unsigned short)tabb_all[L * TAB * 64 + (t + 1) * 64 + c];
        tabp_all[L * TAB * 64 + t * 64 + c] = lo | (hi << 16);
    }
}

// ---------- aggregation: bucketed reads, packed-pair tab, 4-edge ILP ----------
__global__ __launch_bounds__(256) void k_agg(const float2* __restrict__ edata2,
    const int* __restrict__ cnt, const unsigned* __restrict__ tabp,
    const short* __restrict__ nnb, short* __restrict__ aggb)
{
    const float SC = (float)(TAB - 1) / 5.0f;
    int tid = threadIdx.x;
    int c = tid & 63, r = tid >> 6;
    int n = blockIdx.x * 4 + r;
    if (n >= N_NODES) return;
    int m = min(cnt[n], CAP);
    const float2* ed = edata2 + (long)n * CAP;
    float acc = 0.f;
    int e = 0;
    for (; e + 4 <= m; e += 4){
        float2 ev0 = ed[e], ev1 = ed[e+1], ev2 = ed[e+2], ev3 = ed[e+3];
        int s0 = __float_as_int(ev0.y), s1 = __float_as_int(ev1.y);
        int s2 = __float_as_int(ev2.y), s3 = __float_as_int(ev3.y);
        float x0 = ev0.x * SC; int i0 = min((int)x0, TAB - 2); float f0 = x0 - (float)i0;
        float x1 = ev1.x * SC; int i1 = min((int)x1, TAB - 2); float f1 = x1 - (float)i1;
        float x2 = ev2.x * SC; int i2 = min((int)x2, TAB - 2); float f2 = x2 - (float)i2;
        float x3 = ev3.x * SC; int i3 = min((int)x3, TAB - 2); float f3 = x3 - (float)i3;
        unsigned u0 = tabp[i0 * 64 + c], u1 = tabp[i1 * 64 + c];
        unsigned u2 = tabp[i2 * 64 + c], u3 = tabp[i3 * 64 + c];
        float n0 = b2f(nnb[s0 * 64 + c]), n1 = b2f(nnb[s1 * 64 + c]);
        float n2 = b2f(nnb[s2 * 64 + c]), n3 = b2f(nnb[s3 * 64 + c]);
        float w00 = __uint_as_float(u0 << 16), w01 = __uint_as_float(u0 & 0xffff0000u);
        float w10 = __uint_as_float(u1 << 16), w11 = __uint_as_float(u1 & 0xffff0000u);
        float w20 = __uint_as_float(u2 << 16), w21 = __uint_as_float(u2 & 0xffff0000u);
        float w30 = __uint_as_float(u3 << 16), w31 = __uint_as_float(u3 & 0xffff0000u);
        acc += n0 * (w00 + (w01 - w00) * f0);
        acc += n1 * (w10 + (w11 - w10) * f1);
        acc += n2 * (w20 + (w21 - w20) * f2);
        acc += n3 * (w30 + (w31 - w30) * f3);
    }
    for (; e < m; ++e){
        float2 ev = ed[e];
        int s = __float_as_int(ev.y);
        float x = ev.x * SC; int i0 = min((int)x, TAB - 2); float f = x - (float)i0;
        unsigned u = tabp[i0 * 64 + c];
        float w0 = __uint_as_float(u << 16), w1 = __uint_as_float(u & 0xffff0000u);
        acc += b2f(nnb[s * 64 + c]) * (w0 + (w1 - w0) * f);
    }
    aggb[n * 64 + c] = f2b(acc);
}

// ---------- MFMA update (+ fused next-layer conv GEMM): ----------
// node += sp2(agg@nl2+b2)@nl3 + b3 ; if wnext: nnb = node_new @ wnext
__global__ __launch_bounds__(256) void k_update(const short* __restrict__ aggb,
    const short* __restrict__ nl2t, const float* __restrict__ nl2b,
    const short* __restrict__ nl3t, const float* __restrict__ nl3b,
    float* __restrict__ node, short* __restrict__ nodeb,
    const short* __restrict__ wnext, short* __restrict__ nnb)
{
    __shared__ short sT[32 * 80];
    int tid = threadIdx.x, wave = tid >> 6, lane = tid & 63;
    int quad = lane >> 4, l16 = lane & 15;
    int row0 = blockIdx.x * 32;
    int rt = wave >> 1;
    int ctb = (wave & 1) * 2;
    // stage 1: t = sp2(agg@nl2+b2) -> sT
    f32x4 acc[2] = {{0,0,0,0},{0,0,0,0}};
    #pragma unroll
    for (int kt = 0; kt < 2; ++kt){
        int k0 = kt * 32 + quad * 8;
        int rw = row0 + rt * 16 + l16;
        bf16x8 a = (rw < N_NODES) ? *(const bf16x8*)&aggb[rw * 64 + k0] : (bf16x8){0,0,0,0,0,0,0,0};
        #pragma unroll
        for (int i = 0; i < 2; ++i){
            bf16x8 b = *(const bf16x8*)&nl2t[((ctb + i) * 16 + l16) * 64 + k0];
            acc[i] = MFMA16(a, b, acc[i]);
        }
    }
    #pragma unroll
    for (int i = 0; i < 2; ++i)
        #pragma unroll
        for (int reg = 0; reg < 4; ++reg){
            int rl = rt * 16 + quad * 4 + reg;
            int col = (ctb + i) * 16 + l16;
            sT[rl * 80 + col] = f2b(sp2f(acc[i][reg] + nl2b[col]));
        }
    __syncthreads();
    // stage 2: node_new = node + t@nl3 + b3
    f32x4 acc2[2] = {{0,0,0,0},{0,0,0,0}};
    #pragma unroll
    for (int kt = 0; kt < 2; ++kt){
        int k0 = kt * 32 + quad * 8;
        bf16x8 a = *(const bf16x8*)&sT[(rt * 16 + l16) * 80 + k0];
        #pragma unroll
        for (int i = 0; i < 2; ++i){
            bf16x8 b = *(const bf16x8*)&nl3t[((ctb + i) * 16 + l16) * 64 + k0];
            acc2[i] = MFMA16(a, b, acc2[i]);
        }
    }
    short vb[2][4];
    #pragma unroll
    for (int i = 0; i < 2; ++i)
        #pragma unroll
        for (int reg = 0; reg < 4; ++reg){
            int row = row0 + rt * 16 + quad * 4 + reg;
            int col = (ctb + i) * 16 + l16;
            float v = 0.f;
            if (row < N_NODES){
                v = node[row * 64 + col] + acc2[i][reg] + nl3b[col];
                node[row * 64 + col] = v;
            }
            short vbs = f2b(v);
            vb[i][reg] = vbs;
            if (row < N_NODES) nodeb[row * 64 + col] = vbs;
        }
    // stage 3 (fused next-layer conv): nnb = node_new @ wnext
    if (wnext){
        __syncthreads();                       // stage-2 sT reads complete
        #pragma unroll
        for (int i = 0; i < 2; ++i)
            #pragma unroll
            for (int reg = 0; reg < 4; ++reg)
                sT[(rt * 16 + quad * 4 + reg) * 80 + (ctb + i) * 16 + l16] = vb[i][reg];
        __syncthreads();
        f32x4 acc3[2] = {{0,0,0,0},{0,0,0,0}};
        #pragma unroll
        for (int kt = 0; kt < 2; ++kt){
            int k0 = kt * 32 + quad * 8;
            bf16x8 a = *(const bf16x8*)&sT[(rt * 16 + l16) * 80 + k0];
            #pragma unroll
            for (int i = 0; i < 2; ++i){
                bf16x8 b = *(const bf16x8*)&wnext[((ctb + i) * 16 + l16) * 64 + k0];
                acc3[i] = MFMA16(a, b, acc3[i]);
            }
        }
        #pragma unroll
        for (int i = 0; i < 2; ++i)
            #pragma unroll
            for (int reg = 0; reg < 4; ++reg){
                int row = row0 + rt * 16 + quad * 4 + reg;
                int col = (ctb + i) * 16 + l16;
                if (row < N_NODES) nnb[row * 64 + col] = f2b(acc3[i][reg]);
            }
    }
}

// ---------- readout stage 1: atom = ssp(node@d1+b1) ----------
__global__ __launch_bounds__(256) void k_r1(const short* __restrict__ nodeb,
    const short* __restrict__ d1t, const float* __restrict__ d1b,
    short* __restrict__ atomb)
{
    int tid = threadIdx.x, wave = tid >> 6, lane = tid & 63;
    int quad = lane >> 4, l16 = lane & 15;
    int row0 = blockIdx.x * 32;
    f32x4 acc[2][4] = {{{0,0,0,0},{0,0,0,0},{0,0,0,0},{0,0,0,0}},
                       {{0,0,0,0},{0,0,0,0},{0,0,0,0},{0,0,0,0}}};
    #pragma unroll
    for (int kt = 0; kt < 2; ++kt){
        int k0 = kt * 32 + quad * 8;
        bf16x8 a[2];
        #pragma unroll
        for (int rt = 0; rt < 2; ++rt){
            int rw = row0 + rt * 16 + l16;
            a[rt] = (rw < N_NODES) ? *(const bf16x8*)&nodeb[rw * 64 + k0] : (bf16x8){0,0,0,0,0,0,0,0};
        }
        #pragma unroll
        for (int ct = 0; ct < 4; ++ct){
            int n = wave * 64 + ct * 16 + l16;
            bf16x8 b = *(const bf16x8*)&d1t[n * 64 + k0];
            #pragma unroll
            for (int rt = 0; rt < 2; ++rt) acc[rt][ct] = MFMA16(a[rt], b, acc[rt][ct]);
        }
    }
    #pragma unroll
    for (int rt = 0; rt < 2; ++rt)
        #pragma unroll
        for (int ct = 0; ct < 4; ++ct){
            int col = wave * 64 + ct * 16 + l16;
            float bb = d1b[col];
            #pragma unroll
            for (int reg = 0; reg < 4; ++reg){
                int row = row0 + rt * 16 + quad * 4 + reg;
                if (row < N_NODES) atomb[row * HID + col] = f2b(sspf(acc[rt][ct][reg] + bb));
            }
        }
}

// ---------- readout stage 2: res = atom@d2+b2; pool; resb = bf16(relu(res)) ----------
__global__ __launch_bounds__(256) void k_r2(const short* __restrict__ atomb,
    const short* __restrict__ d2t, const float* __restrict__ d2b_,
    const int* __restrict__ gid, float* __restrict__ gacc, short* __restrict__ resb)
{
    __shared__ float sres[32 * 260];
    int tid = threadIdx.x, wave = tid >> 6, lane = tid & 63;
    int quad = lane >> 4, l16 = lane & 15;
    int row0 = blockIdx.x * 32;
    f32x4 acc[2][4] = {{{0,0,0,0},{0,0,0,0},{0,0,0,0},{0,0,0,0}},
                       {{0,0,0,0},{0,0,0,0},{0,0,0,0},{0,0,0,0}}};
    for (int kt = 0; kt < 8; ++kt){
        int k0 = kt * 32 + quad * 8;
        bf16x8 a[2];
        #pragma unroll
        for (int rt = 0; rt < 2; ++rt){
            int rw = row0 + rt * 16 + l16;
            a[rt] = (rw < N_NODES) ? *(const bf16x8*)&atomb[rw * HID + k0] : (bf16x8){0,0,0,0,0,0,0,0};
        }
        #pragma unroll
        for (int ct = 0; ct < 4; ++ct){
            int n = wave * 64 + ct * 16 + l16;
            bf16x8 b = *(const bf16x8*)&d2t[n * HID + k0];
            #pragma unroll
            for (int rt = 0; rt < 2; ++rt) acc[rt][ct] = MFMA16(a[rt], b, acc[rt][ct]);
        }
    }
    #pragma unroll
    for (int rt = 0; rt < 2; ++rt)
        #pragma unroll
        for (int ct = 0; ct < 4; ++ct){
            int col = wave * 64 + ct * 16 + l16;
            float bb = d2b_[col];
            #pragma unroll
            for (int reg = 0; reg < 4; ++reg){
                int rl = rt * 16 + quad * 4 + reg;
                sres[rl * 260 + col] = acc[rt][ct][reg] + bb;
            }
        }
    __syncthreads();
    float run = 0.f; int cur = -1;
    for (int r = 0; r < 32; ++r){
        int n = row0 + r;
        if (n >= N_NODES) break;
        float v = sres[r * 260 + tid];
        int g = gid[n];
        if (g != cur){
            if (cur >= 0) atomicAdd(&gacc[cur * HID + tid], run);
            run = 0.f; cur = g;
        }
        run += v;
        resb[n * HID + tid] = f2b(fmaxf(v, 0.f));
    }
    if (cur >= 0) atomicAdd(&gacc[cur * HID + tid], run);
}

// ---------- readout stage 3: atoms_preds = resb@ac + b ----------
__global__ __launch_bounds__(256) void k_r3(const short* __restrict__ resb,
    const short* __restrict__ act, const float* __restrict__ acb,
    float* __restrict__ out_atoms)
{
    int tid = threadIdx.x, wave = tid >> 6, lane = tid & 63;
    int quad = lane >> 4, l16 = lane & 15;
    int row0 = blockIdx.x * 64;
    f32x4 acc[7] = {{0,0,0,0},{0,0,0,0},{0,0,0,0},{0,0,0,0},{0,0,0,0},{0,0,0,0},{0,0,0,0}};
    for (int kt = 0; kt < 8; ++kt){
        int k0 = kt * 32 + quad * 8;
        int rw = row0 + wave * 16 + l16;
        bf16x8 a = (rw < N_NODES) ? *(const bf16x8*)&resb[rw * HID + k0] : (bf16x8){0,0,0,0,0,0,0,0};
        #pragma unroll
        for (int ct = 0; ct < 7; ++ct){
            bf16x8 b = *(const bf16x8*)&act[(ct * 16 + l16) * HID + k0];
            acc[ct] = MFMA16(a, b, acc[ct]);
        }
    }
    #pragma unroll
    for (int ct = 0; ct < 7; ++ct){
        int col = ct * 16 + l16;
        if (col >= ACT_DIM) continue;
        float bb = acb[col];
        #pragma unroll
        for (int reg = 0; reg < 4; ++reg){
            int row = row0 + wave * 16 + quad * 4 + reg;
            if (row < N_NODES) out_atoms[row * ACT_DIM + col] = acc[ct][reg] + bb;
        }
    }
}

__global__ void k_embg(const float* __restrict__ gacc, const float* __restrict__ counts,
                       short* __restrict__ gclsb){
    int i = blockIdx.x * 256 + threadIdx.x;
    if (i < N_GRAPHS * HID){
        int g = i >> 8;
        gclsb[i] = f2b(gacc[i] / fmaxf(counts[g], 1.0f));
    }
}

__global__ __launch_bounds__(256) void k_cls2(const short* __restrict__ gclsb,
    const short* __restrict__ clswt, const float* __restrict__ clsb,
    float* __restrict__ out_cls)
{
    int tid = threadIdx.x, wave = tid >> 6, lane = tid & 63;
    int quad = lane >> 4, l16 = lane & 15;
    int row0 = blockIdx.x * 32;
    int colbase = blockIdx.y * 256 + wave * 64;
    f32x4 acc[2][4] = {{{0,0,0,0},{0,0,0,0},{0,0,0,0},{0,0,0,0}},
                       {{0,0,0,0},{0,0,0,0},{0,0,0,0},{0,0,0,0}}};
    for (int kt = 0; kt < 8; ++kt){
        int k0 = kt * 32 + quad * 8;
        bf16x8 a[2];
        #pragma unroll
        for (int rt = 0; rt < 2; ++rt){
            int rw = row0 + rt * 16 + l16;
            a[rt] = (rw < N_GRAPHS) ? *(const bf16x8*)&gclsb[rw * HID + k0] : (bf16x8){0,0,0,0,0,0,0,0};
        }
        #pragma unroll
        for (int ct = 0; ct < 4; ++ct){
            bf16x8 b = *(const bf16x8*)&clswt[(colbase + ct * 16 + l16) * HID + k0];
            #pragma unroll
            for (int rt = 0; rt < 2; ++rt) acc[rt][ct] = MFMA16(a[rt], b, acc[rt][ct]);
        }
    }
    #pragma unroll
    for (int rt = 0; rt < 2; ++rt)
        #pragma unroll
        for (int ct = 0; ct < 4; ++ct){
            int col = colbase + ct * 16 + l16;
            if (col >= CLS_DIM) continue;
            float bb = clsb[col];
            #pragma unroll
            for (int reg = 0; reg < 4; ++reg){
                int row = row0 + rt * 16 + quad * 4 + reg;
                if (row < N_GRAPHS) out_cls[row * CLS_DIM + col] = acc[rt][ct][reg] + bb;
            }
        }
}

extern "C" void kernel_launch(void* const* d_in, const int* in_sizes, int n_in,
                              void* d_out, int out_size, void* d_ws, size_t ws_size,
                              hipStream_t stream)
{
    const int*   node_types = (const int*)d_in[0];
    const int*   edge_src   = (const int*)d_in[1];
    const int*   edge_dst   = (const int*)d_in[2];
    const int*   graph_ids  = (const int*)d_in[3];
    const float* distance   = (const float*)d_in[4];
    const float* emb        = (const float*)d_in[5];
    const float* conv_w1    = (const float*)d_in[6];
    const float* cf1_w      = (const float*)d_in[7];
    const float* cf1_b      = (const float*)d_in[8];
    const float* cf2_w      = (const float*)d_in[9];
    const float* cf2_b      = (const float*)d_in[10];
    const float* nl2_w      = (const float*)d_in[11];
    const float* nl2_b      = (const float*)d_in[12];
    const float* nl3_w      = (const float*)d_in[13];
    const float* nl3_b      = (const float*)d_in[14];
    const float* d1_w       = (const float*)d_in[15];
    const float* d1_b       = (const float*)d_in[16];
    const float* d2_w       = (const float*)d_in[17];
    const float* d2_b       = (const float*)d_in[18];
    const float* cls_w      = (const float*)d_in[19];
    const float* cls_b      = (const float*)d_in[20];
    const float* ac_w       = (const float*)d_in[21];
    const float* ac_b       = (const float*)d_in[22];

    // ---- workspace layout (16B-aligned; ~62 MB) ----
    float*    node   = (float*)d_ws;                   // 3,200,000 f
    float*    gacc   = node + 3200000;                 // 128,000 f
    float*    counts = gacc + 128000;                  // 512 f
    float2*   edata2 = (float2*)(counts + 512);        // 3,200,000 f2 (50k x CAP)
    int*      cnt    = (int*)(edata2 + 3200000);       // 50,048 i
    short*    nodeb  = (short*)(cnt + 50048);          // 3,200,000
    short*    nnb    = nodeb + 3200000;                // 3,200,000
    short*    aggb   = nnb + 3200000;                  // 3,200,000
    short*    tabb   = aggb + 3200000;                 // 3 * 131,072
    unsigned* tabp   = (unsigned*)(tabb + 3 * 131072); // 3 * 131,072 u32
    short*    cw1t   = (short*)(tabp + 3 * 131072);    // 12,288
    short*    n2t    = cw1t + 12288;                   // 12,288
    short*    n3t    = n2t + 12288;                    // 12,288
    short*    d1t    = n3t + 12288;                    // 16,384
    short*    d2t    = d1t + 16384;                    // 65,536
    short*    act    = d2t + 65536;                    // 28,672
    short*    clswt  = act + 28672;                    // 524,288
    short*    gclsb  = clswt + 524288;                 // 128,000
    short*    embw0b = gclsb + 128000;                 // 6,400
    short*    atomb  = (short*)edata2;                 // ALIAS: edata2 dead after conv loop
    short*    resb   = atomb;                          // ALIAS: k_r2 reads atom rows first
    float*    out    = (float*)d_out;

    (void)hipMemsetAsync(gacc, 0, (128000 + 512) * sizeof(float), stream);
    (void)hipMemsetAsync(cnt, 0, 50048 * sizeof(int), stream);

    k_tw<<<2649, 256, 0, stream>>>(conv_w1, nl2_w, nl3_w, d1_w, d2_w, ac_w, cls_w, emb,
                                   cw1t, n2t, n3t, d1t, d2t, act, clswt, embw0b);
    k_table3<<<dim3(TAB / 4, 3), 256, 0, stream>>>(cf1_w, cf1_b, cf2_w, cf2_b, tabb);
    k_pack<<<dim3(512, 3), 256, 0, stream>>>(tabb, tabp);

    k_embed<<<(N_NODES * DIM + 255) / 256, 256, 0, stream>>>(node_types, emb, embw0b,
        node, nodeb, nnb, graph_ids, counts);
    k_scatter2<<<(N_EDGES + 255) / 256, 256, 0, stream>>>(edge_src, edge_dst, distance,
                                                          cnt, edata2);

    for (int i = 0; i < N_CONV; ++i){
        k_agg<<<(N_NODES + 3) / 4, 256, 0, stream>>>(edata2, cnt, tabp + i * TAB * 64,
                                                     nnb, aggb);
        k_update<<<(N_NODES + 31) / 32, 256, 0, stream>>>(aggb,
            n2t + i * 4096, nl2_b + i * DIM, n3t + i * 4096, nl3_b + i * DIM,
            node, nodeb, (i < N_CONV - 1) ? (cw1t + (i + 1) * 4096) : (const short*)nullptr, nnb);
    }

    k_r1<<<(N_NODES + 31) / 32, 256, 0, stream>>>(nodeb, d1t, d1_b, atomb);
    k_r2<<<(N_NODES + 31) / 32, 256, 0, stream>>>(atomb, d2t, d2_b, graph_ids, gacc, resb);
    k_r3<<<(N_NODES + 63) / 64, 256, 0, stream>>>(resb, act, ac_b, out);
    k_embg<<<(N_GRAPHS * HID + 255) / 256, 256, 0, stream>>>(gacc, counts, gclsb);
    k_cls2<<<dim3((N_GRAPHS + 31) / 32, (CLS_DIM + 255) / 256), 256, 0, stream>>>(
        gclsb, clswt, cls_b, out + N_NODES * ACT_DIM);
}

// Round 9
// 492.848 us; speedup vs baseline: 4.0421x; 1.0797x over previous
//
#include <hip/hip_runtime.h>
#include <math.h>

#define N_NODES 50000
#define N_EDGES 800000
#define N_GRAPHS 500
#define DIM 64
#define RBF_DIM 5
#define N_CONV 3
#define CLS_DIM 2000
#define ACT_DIM 100
#define HID 256
#define TAB 2048
#define CAP 64            // max in-degree capacity (Poisson(16): P(>=64)~1e-55)

typedef __attribute__((ext_vector_type(8))) short bf16x8;
typedef __attribute__((ext_vector_type(4))) float f32x4;
#define MFMA16(a,b,c) __builtin_amdgcn_mfma_f32_16x16x32_bf16(a,b,c,0,0,0)

__device__ __forceinline__ float sp2f(float x){
    float y = 0.5f * x;
    return 2.0f * (fmaxf(y, 0.0f) + log1pf(__expf(-fabsf(y))));
}
__device__ __forceinline__ float sspf(float x){
    return fmaxf(x, 0.0f) + log1pf(__expf(-fabsf(x))) - 0.69314718055994531f;
}
__device__ __forceinline__ short f2b(float x){
    union { float f; unsigned u; } v; v.f = x;
    unsigned r = v.u + 0x7FFFu + ((v.u >> 16) & 1u);
    return (short)(r >> 16);
}
__device__ __forceinline__ float b2f(short x){
    union { unsigned u; float f; } v; v.u = ((unsigned)(unsigned short)x) << 16;
    return v.f;
}

// ---------- fused weight prep: 7 transposes + embW0 = emb @ conv_w1[0] ----------
__global__ void k_tw(const float* __restrict__ cw, const float* __restrict__ n2,
                     const float* __restrict__ n3, const float* __restrict__ d1w,
                     const float* __restrict__ d2w, const float* __restrict__ acw,
                     const float* __restrict__ clsw, const float* __restrict__ emb,
                     short* __restrict__ cwt, short* __restrict__ n2t, short* __restrict__ n3t,
                     short* __restrict__ d1t, short* __restrict__ d2t, short* __restrict__ act,
                     short* __restrict__ clswt, short* __restrict__ embw0b){
    int b = blockIdx.x, tid = threadIdx.x;
    if (b < 144){                                  // 9x 64x64
        int i = b * 256 + tid;
        int y = i >> 12, j = i & 4095;
        int which = y / 3, layer = y % 3;
        const float* src = (which == 0 ? cw : which == 1 ? n2 : n3) + layer * 4096;
        short* dst = (which == 0 ? cwt : which == 1 ? n2t : n3t) + layer * 4096;
        int k = j >> 6, n = j & 63;
        dst[n * 64 + k] = f2b(src[k * 64 + n]);
    } else if (b < 208){                           // d1 64x256
        int i = (b - 144) * 256 + tid;
        int k = i >> 8, n = i & 255;
        d1t[n * 64 + k] = f2b(d1w[k * 256 + n]);
    } else if (b < 464){                           // d2 256x256
        int i = (b - 208) * 256 + tid;
        int k = i >> 8, n = i & 255;
        d2t[n * 256 + k] = f2b(d2w[k * 256 + n]);
    } else if (b < 576){                           // ac 256x100 -> pad 112
        int i = (b - 464) * 256 + tid;
        int n = i >> 8, k = i & 255;
        act[n * 256 + k] = f2b(n < ACT_DIM ? acw[k * ACT_DIM + n] : 0.f);
    } else if (b < 2624){                          // cls 256x2000 -> pad 2048
        int i = (b - 576) * 256 + tid;
        int k = i >> 11, n = i & 2047;
        clswt[n * 256 + k] = f2b(n < CLS_DIM ? clsw[k * CLS_DIM + n] : 0.f);
    } else {                                       // embW0 = emb @ conv_w1[0]  (100x64)
        int i = (b - 2624) * 256 + tid;
        if (i < 100 * 64){
            int t = i >> 6, c = i & 63;
            float a = 0.f;
            #pragma unroll 8
            for (int k = 0; k < 64; ++k) a += emb[t * 64 + k] * cw[k * 64 + c];
            embw0b[i] = f2b(a);
        }
    }
}

// ---------- fused: embed gather + nnb(L0) gather + counts + bucketed edge scatter ----------
// edge payload: (v<<17)|src, v = round(d*SC*16) 15-bit quantized table coord
__global__ void k_embed(const int* __restrict__ types, const float* __restrict__ emb,
                        const short* __restrict__ embw0b,
                        float* __restrict__ node, short* __restrict__ nodeb,
                        short* __restrict__ nnb,
                        const int* __restrict__ gid, float* __restrict__ counts,
                        const int* __restrict__ esrc, const int* __restrict__ edst,
                        const float* __restrict__ dist,
                        int* __restrict__ cnt, unsigned* __restrict__ edata){
    int i = blockIdx.x * 256 + threadIdx.x;
    if (i < N_NODES * DIM){
        int t = types[i >> 6], c = i & 63;
        float v = emb[t * 64 + c];
        node[i] = v; nodeb[i] = f2b(v);
        nnb[i] = embw0b[t * 64 + c];
    }
    if (i < N_EDGES){
        int d = edst[i];
        int pos = atomicAdd(&cnt[d], 1);
        if (pos < CAP){
            const float SC16 = (float)(TAB - 1) * 16.0f / 5.0f;
            int v = (int)(dist[i] * SC16 + 0.5f);
            v = min(v, 32767);
            edata[d * CAP + pos] = ((unsigned)v << 17) | (unsigned)esrc[i];
        }
    }
    if (i < N_NODES) atomicAdd(&counts[gid[i]], 1.0f);
}

// ---------- all 3 layers' filter tables ----------
__global__ __launch_bounds__(256) void k_table3(const float* __restrict__ cf1w_all,
    const float* __restrict__ cf1b_all, const float* __restrict__ cf2w_all,
    const float* __restrict__ cf2b_all, short* __restrict__ tabb_all)
{
    int L = blockIdx.y;
    const float* cf1w = cf1w_all + L * RBF_DIM * DIM;
    const float* cf1b = cf1b_all + L * DIM;
    const float* cf2w = cf2w_all + L * DIM * DIM;
    const float* cf2b = cf2b_all + L * DIM;
    short* tabb = tabb_all + L * TAB * 64;
    __shared__ float s_cf1[RBF_DIM * 64];
    __shared__ float s_cf1b[64], s_cf2b[64];
    __shared__ float s_cf2[64 * 64];
    __shared__ float s_h1[4 * 64];
    int tid = threadIdx.x;
    int c = tid & 63, g = tid >> 6;
    for (int i = tid; i < 64 * 64; i += 256) s_cf2[i] = cf2w[i];
    for (int i = tid; i < RBF_DIM * 64; i += 256) s_cf1[i] = cf1w[i];
    if (tid < 64){ s_cf1b[tid] = cf1b[tid]; s_cf2b[tid] = cf2b[tid]; }
    __syncthreads();
    int entry = blockIdx.x * 4 + g;
    float d = (float)entry * (5.0f / (float)(TAB - 1));
    {
        float acc = s_cf1b[c];
        #pragma unroll
        for (int j = 0; j < RBF_DIM; ++j){
            float t = d - 1.25f * (float)j;
            acc += __expf(-0.8f * t * t) * s_cf1[j * 64 + c];
        }
        s_h1[g * 64 + c] = sp2f(acc);
    }
    __syncthreads();
    {
        float acc = s_cf2b[c];
        #pragma unroll 8
        for (int k = 0; k < 64; ++k) acc += s_h1[g * 64 + k] * s_cf2[k * 64 + c];
        tabb[entry * 64 + c] = f2b(sp2f(acc));
    }
}

// pack adjacent table entries: tabp[t][c] = (eh[t][c], eh[t+1][c]) as one uint
__global__ void k_pack(const short* __restrict__ tabb_all, unsigned* __restrict__ tabp_all){
    int L = blockIdx.y;
    int i = blockIdx.x * 256 + threadIdx.x;
    if (i < (TAB - 1) * 64){
        int t = i >> 6, c = i & 63;
        unsigned lo = (unsigned short)tabb_all[L * TAB * 64 + t * 64 + c];
        unsigned hi = (unsigned short)tabb_all[L * TAB * 64 + (t + 1) * 64 + c];
        tabp_all[L * TAB * 64 + t * 64 + c] = lo | (hi << 16);
    }
}

// ---------- aggregation: lane-parallel bucket preload + shfl broadcast ----------
__global__ __launch_bounds__(256) void k_agg(const unsigned* __restrict__ edata,
    const int* __restrict__ cnt, const unsigned* __restrict__ tabp,
    const short* __restrict__ nnb, short* __restrict__ aggb)
{
    int tid = threadIdx.x;
    int c = tid & 63, r = tid >> 6;
    int n = blockIdx.x * 4 + r;
    if (n >= N_NODES) return;
    int m = min(cnt[n], CAP);
    const unsigned* ed = edata + (long)n * CAP;
    // lane e preloads edge e of this node's bucket (one coalesced wave load)
    unsigned ev = (c < m) ? ed[c] : 0u;
    int s_l = (int)(ev & 0x1FFFFu);
    int v_l = (int)(ev >> 17);
    int i0_l = min(v_l >> 4, TAB - 2);
    float f_l = (float)(v_l - (i0_l << 4)) * 0.0625f;
    int pk_l = (i0_l << 17) | s_l;         // i0:11b | s:17b
    float acc = 0.f;
    int e = 0;
    for (; e + 4 <= m; e += 4){
        int   pa = __shfl(pk_l, e);     float fa = __shfl(f_l, e);
        int   pb = __shfl(pk_l, e + 1); float fb = __shfl(f_l, e + 1);
        int   pc = __shfl(pk_l, e + 2); float fc = __shfl(f_l, e + 2);
        int   pd = __shfl(pk_l, e + 3); float fd = __shfl(f_l, e + 3);
        int ia = pa >> 17, sa = pa & 0x1FFFF;
        int ib = pb >> 17, sb = pb & 0x1FFFF;
        int ic = pc >> 17, sc = pc & 0x1FFFF;
        int id = pd >> 17, sd = pd & 0x1FFFF;
        unsigned ua = tabp[ia * 64 + c], ub = tabp[ib * 64 + c];
        unsigned uc = tabp[ic * 64 + c], ud = tabp[id * 64 + c];
        float na = b2f(nnb[sa * 64 + c]), nb = b2f(nnb[sb * 64 + c]);
        float nc = b2f(nnb[sc * 64 + c]), nd = b2f(nnb[sd * 64 + c]);
        float wa0 = __uint_as_float(ua << 16), wa1 = __uint_as_float(ua & 0xffff0000u);
        float wb0 = __uint_as_float(ub << 16), wb1 = __uint_as_float(ub & 0xffff0000u);
        float wc0 = __uint_as_float(uc << 16), wc1 = __uint_as_float(uc & 0xffff0000u);
        float wd0 = __uint_as_float(ud << 16), wd1 = __uint_as_float(ud & 0xffff0000u);
        acc += na * (wa0 + (wa1 - wa0) * fa);
        acc += nb * (wb0 + (wb1 - wb0) * fb);
        acc += nc * (wc0 + (wc1 - wc0) * fc);
        acc += nd * (wd0 + (wd1 - wd0) * fd);
    }
    for (; e < m; ++e){
        int   p = __shfl(pk_l, e); float f = __shfl(f_l, e);
        int i0 = p >> 17, s = p & 0x1FFFF;
        unsigned u = tabp[i0 * 64 + c];
        float w0 = __uint_as_float(u << 16), w1 = __uint_as_float(u & 0xffff0000u);
        acc += b2f(nnb[s * 64 + c]) * (w0 + (w1 - w0) * f);
    }
    aggb[n * 64 + c] = f2b(acc);
}

// ---------- MFMA update (+ fused next-layer conv GEMM) ----------
__global__ __launch_bounds__(256) void k_update(const short* __restrict__ aggb,
    const short* __restrict__ nl2t, const float* __restrict__ nl2b,
    const short* __restrict__ nl3t, const float* __restrict__ nl3b,
    float* __restrict__ node, short* __restrict__ nodeb,
    const short* __restrict__ wnext, short* __restrict__ nnb)
{
    __shared__ short sT[32 * 80];
    int tid = threadIdx.x, wave = tid >> 6, lane = tid & 63;
    int quad = lane >> 4, l16 = lane & 15;
    int row0 = blockIdx.x * 32;
    int rt = wave >> 1;
    int ctb = (wave & 1) * 2;
    f32x4 acc[2] = {{0,0,0,0},{0,0,0,0}};
    #pragma unroll
    for (int kt = 0; kt < 2; ++kt){
        int k0 = kt * 32 + quad * 8;
        int rw = row0 + rt * 16 + l16;
        bf16x8 a = (rw < N_NODES) ? *(const bf16x8*)&aggb[rw * 64 + k0] : (bf16x8){0,0,0,0,0,0,0,0};
        #pragma unroll
        for (int i = 0; i < 2; ++i){
            bf16x8 b = *(const bf16x8*)&nl2t[((ctb + i) * 16 + l16) * 64 + k0];
            acc[i] = MFMA16(a, b, acc[i]);
        }
    }
    #pragma unroll
    for (int i = 0; i < 2; ++i)
        #pragma unroll
        for (int reg = 0; reg < 4; ++reg){
            int rl = rt * 16 + quad * 4 + reg;
            int col = (ctb + i) * 16 + l16;
            sT[rl * 80 + col] = f2b(sp2f(acc[i][reg] + nl2b[col]));
        }
    __syncthreads();
    f32x4 acc2[2] = {{0,0,0,0},{0,0,0,0}};
    #pragma unroll
    for (int kt = 0; kt < 2; ++kt){
        int k0 = kt * 32 + quad * 8;
        bf16x8 a = *(const bf16x8*)&sT[(rt * 16 + l16) * 80 + k0];
        #pragma unroll
        for (int i = 0; i < 2; ++i){
            bf16x8 b = *(const bf16x8*)&nl3t[((ctb + i) * 16 + l16) * 64 + k0];
            acc2[i] = MFMA16(a, b, acc2[i]);
        }
    }
    short vb[2][4];
    #pragma unroll
    for (int i = 0; i < 2; ++i)
        #pragma unroll
        for (int reg = 0; reg < 4; ++reg){
            int row = row0 + rt * 16 + quad * 4 + reg;
            int col = (ctb + i) * 16 + l16;
            float v = 0.f;
            if (row < N_NODES){
                v = node[row * 64 + col] + acc2[i][reg] + nl3b[col];
                node[row * 64 + col] = v;
            }
            short vbs = f2b(v);
            vb[i][reg] = vbs;
            if (row < N_NODES) nodeb[row * 64 + col] = vbs;
        }
    if (wnext){
        __syncthreads();
        #pragma unroll
        for (int i = 0; i < 2; ++i)
            #pragma unroll
            for (int reg = 0; reg < 4; ++reg)
                sT[(rt * 16 + quad * 4 + reg) * 80 + (ctb + i) * 16 + l16] = vb[i][reg];
        __syncthreads();
        f32x4 acc3[2] = {{0,0,0,0},{0,0,0,0}};
        #pragma unroll
        for (int kt = 0; kt < 2; ++kt){
            int k0 = kt * 32 + quad * 8;
            bf16x8 a = *(const bf16x8*)&sT[(rt * 16 + l16) * 80 + k0];
            #pragma unroll
            for (int i = 0; i < 2; ++i){
                bf16x8 b = *(const bf16x8*)&wnext[((ctb + i) * 16 + l16) * 64 + k0];
                acc3[i] = MFMA16(a, b, acc3[i]);
            }
        }
        #pragma unroll
        for (int i = 0; i < 2; ++i)
            #pragma unroll
            for (int reg = 0; reg < 4; ++reg){
                int row = row0 + rt * 16 + quad * 4 + reg;
                int col = (ctb + i) * 16 + l16;
                if (row < N_NODES) nnb[row * 64 + col] = f2b(acc3[i][reg]);
            }
    }
}

// ---------- readout stage 1: atom = ssp(node@d1+b1) ----------
__global__ __launch_bounds__(256) void k_r1(const short* __restrict__ nodeb,
    const short* __restrict__ d1t, const float* __restrict__ d1b,
    short* __restrict__ atomb)
{
    int tid = threadIdx.x, wave = tid >> 6, lane = tid & 63;
    int quad = lane >> 4, l16 = lane & 15;
    int row0 = blockIdx.x * 32;
    f32x4 acc[2][4] = {{{0,0,0,0},{0,0,0,0},{0,0,0,0},{0,0,0,0}},
                       {{0,0,0,0},{0,0,0,0},{0,0,0,0},{0,0,0,0}}};
    #pragma unroll
    for (int kt = 0; kt < 2; ++kt){
        int k0 = kt * 32 + quad * 8;
        bf16x8 a[2];
        #pragma unroll
        for (int rt = 0; rt < 2; ++rt){
            int rw = row0 + rt * 16 + l16;
            a[rt] = (rw < N_NODES) ? *(const bf16x8*)&nodeb[rw * 64 + k0] : (bf16x8){0,0,0,0,0,0,0,0};
        }
        #pragma unroll
        for (int ct = 0; ct < 4; ++ct){
            int n = wave * 64 + ct * 16 + l16;
            bf16x8 b = *(const bf16x8*)&d1t[n * 64 + k0];
            #pragma unroll
            for (int rt = 0; rt < 2; ++rt) acc[rt][ct] = MFMA16(a[rt], b, acc[rt][ct]);
        }
    }
    #pragma unroll
    for (int rt = 0; rt < 2; ++rt)
        #pragma unroll
        for (int ct = 0; ct < 4; ++ct){
            int col = wave * 64 + ct * 16 + l16;
            float bb = d1b[col];
            #pragma unroll
            for (int reg = 0; reg < 4; ++reg){
                int row = row0 + rt * 16 + quad * 4 + reg;
                if (row < N_NODES) atomb[row * HID + col] = f2b(sspf(acc[rt][ct][reg] + bb));
            }
        }
}

// ---------- readout stage 2: res = atom@d2+b2; pool; resb = bf16(relu(res)) ----------
__global__ __launch_bounds__(256) void k_r2(const short* __restrict__ atomb,
    const short* __restrict__ d2t, const float* __restrict__ d2b_,
    const int* __restrict__ gid, float* __restrict__ gacc, short* __restrict__ resb)
{
    __shared__ float sres[32 * 260];
    int tid = threadIdx.x, wave = tid >> 6, lane = tid & 63;
    int quad = lane >> 4, l16 = lane & 15;
    int row0 = blockIdx.x * 32;
    f32x4 acc[2][4] = {{{0,0,0,0},{0,0,0,0},{0,0,0,0},{0,0,0,0}},
                       {{0,0,0,0},{0,0,0,0},{0,0,0,0},{0,0,0,0}}};
    for (int kt = 0; kt < 8; ++kt){
        int k0 = kt * 32 + quad * 8;
        bf16x8 a[2];
        #pragma unroll
        for (int rt = 0; rt < 2; ++rt){
            int rw = row0 + rt * 16 + l16;
            a[rt] = (rw < N_NODES) ? *(const bf16x8*)&atomb[rw * HID + k0] : (bf16x8){0,0,0,0,0,0,0,0};
        }
        #pragma unroll
        for (int ct = 0; ct < 4; ++ct){
            int n = wave * 64 + ct * 16 + l16;
            bf16x8 b = *(const bf16x8*)&d2t[n * HID + k0];
            #pragma unroll
            for (int rt = 0; rt < 2; ++rt) acc[rt][ct] = MFMA16(a[rt], b, acc[rt][ct]);
        }
    }
    #pragma unroll
    for (int rt = 0; rt < 2; ++rt)
        #pragma unroll
        for (int ct = 0; ct < 4; ++ct){
            int col = wave * 64 + ct * 16 + l16;
            float bb = d2b_[col];
            #pragma unroll
            for (int reg = 0; reg < 4; ++reg){
                int rl = rt * 16 + quad * 4 + reg;
                sres[rl * 260 + col] = acc[rt][ct][reg] + bb;
            }
        }
    __syncthreads();
    float run = 0.f; int cur = -1;
    for (int r = 0; r < 32; ++r){
        int n = row0 + r;
        if (n >= N_NODES) break;
        float v = sres[r * 260 + tid];
        int g = gid[n];
        if (g != cur){
            if (cur >= 0) atomicAdd(&gacc[cur * HID + tid], run);
            run = 0.f; cur = g;
        }
        run += v;
        resb[n * HID + tid] = f2b(fmaxf(v, 0.f));
    }
    if (cur >= 0) atomicAdd(&gacc[cur * HID + tid], run);
}

// ---------- readout stage 3: atoms_preds = resb@ac + b ----------
__global__ __launch_bounds__(256) void k_r3(const short* __restrict__ resb,
    const short* __restrict__ act, const float* __restrict__ acb,
    float* __restrict__ out_atoms)
{
    int tid = threadIdx.x, wave = tid >> 6, lane = tid & 63;
    int quad = lane >> 4, l16 = lane & 15;
    int row0 = blockIdx.x * 64;
    f32x4 acc[7] = {{0,0,0,0},{0,0,0,0},{0,0,0,0},{0,0,0,0},{0,0,0,0},{0,0,0,0},{0,0,0,0}};
    for (int kt = 0; kt < 8; ++kt){
        int k0 = kt * 32 + quad * 8;
        int rw = row0 + wave * 16 + l16;
        bf16x8 a = (rw < N_NODES) ? *(const bf16x8*)&resb[rw * HID + k0] : (bf16x8){0,0,0,0,0,0,0,0};
        #pragma unroll
        for (int ct = 0; ct < 7; ++ct){
            bf16x8 b = *(const bf16x8*)&act[(ct * 16 + l16) * HID + k0];
            acc[ct] = MFMA16(a, b, acc[ct]);
        }
    }
    #pragma unroll
    for (int ct = 0; ct < 7; ++ct){
        int col = ct * 16 + l16;
        if (col >= ACT_DIM) continue;
        float bb = acb[col];
        #pragma unroll
        for (int reg = 0; reg < 4; ++reg){
            int row = row0 + wave * 16 + quad * 4 + reg;
            if (row < N_NODES) out_atoms[row * ACT_DIM + col] = acc[ct][reg] + bb;
        }
    }
}

__global__ void k_embg(const float* __restrict__ gacc, const float* __restrict__ counts,
                       short* __restrict__ gclsb){
    int i = blockIdx.x * 256 + threadIdx.x;
    if (i < N_GRAPHS * HID){
        int g = i >> 8;
        gclsb[i] = f2b(gacc[i] / fmaxf(counts[g], 1.0f));
    }
}

__global__ __launch_bounds__(256) void k_cls2(const short* __restrict__ gclsb,
    const short* __restrict__ clswt, const float* __restrict__ clsb,
    float* __restrict__ out_cls)
{
    int tid = threadIdx.x, wave = tid >> 6, lane = tid & 63;
    int quad = lane >> 4, l16 = lane & 15;
    int row0 = blockIdx.x * 32;
    int colbase = blockIdx.y * 256 + wave * 64;
    f32x4 acc[2][4] = {{{0,0,0,0},{0,0,0,0},{0,0,0,0},{0,0,0,0}},
                       {{0,0,0,0},{0,0,0,0},{0,0,0,0},{0,0,0,0}}};
    for (int kt = 0; kt < 8; ++kt){
        int k0 = kt * 32 + quad * 8;
        bf16x8 a[2];
        #pragma unroll
        for (int rt = 0; rt < 2; ++rt){
            int rw = row0 + rt * 16 + l16;
            a[rt] = (rw < N_GRAPHS) ? *(const bf16x8*)&gclsb[rw * HID + k0] : (bf16x8){0,0,0,0,0,0,0,0};
        }
        #pragma unroll
        for (int ct = 0; ct < 4; ++ct){
            bf16x8 b = *(const bf16x8*)&clswt[(colbase + ct * 16 + l16) * HID + k0];
            #pragma unroll
            for (int rt = 0; rt < 2; ++rt) acc[rt][ct] = MFMA16(a[rt], b, acc[rt][ct]);
        }
    }
    #pragma unroll
    for (int rt = 0; rt < 2; ++rt)
        #pragma unroll
        for (int ct = 0; ct < 4; ++ct){
            int col = colbase + ct * 16 + l16;
            if (col >= CLS_DIM) continue;
            float bb = clsb[col];
            #pragma unroll
            for (int reg = 0; reg < 4; ++reg){
                int row = row0 + rt * 16 + quad * 4 + reg;
                if (row < N_GRAPHS) out_cls[row * CLS_DIM + col] = acc[rt][ct][reg] + bb;
            }
        }
}

extern "C" void kernel_launch(void* const* d_in, const int* in_sizes, int n_in,
                              void* d_out, int out_size, void* d_ws, size_t ws_size,
                              hipStream_t stream)
{
    const int*   node_types = (const int*)d_in[0];
    const int*   edge_src   = (const int*)d_in[1];
    const int*   edge_dst   = (const int*)d_in[2];
    const int*   graph_ids  = (const int*)d_in[3];
    const float* distance   = (const float*)d_in[4];
    const float* emb        = (const float*)d_in[5];
    const float* conv_w1    = (const float*)d_in[6];
    const float* cf1_w      = (const float*)d_in[7];
    const float* cf1_b      = (const float*)d_in[8];
    const float* cf2_w      = (const float*)d_in[9];
    const float* cf2_b      = (const float*)d_in[10];
    const float* nl2_w      = (const float*)d_in[11];
    const float* nl2_b      = (const float*)d_in[12];
    const float* nl3_w      = (const float*)d_in[13];
    const float* nl3_b      = (const float*)d_in[14];
    const float* d1_w       = (const float*)d_in[15];
    const float* d1_b       = (const float*)d_in[16];
    const float* d2_w       = (const float*)d_in[17];
    const float* d2_b       = (const float*)d_in[18];
    const float* cls_w      = (const float*)d_in[19];
    const float* cls_b      = (const float*)d_in[20];
    const float* ac_w       = (const float*)d_in[21];
    const float* ac_b       = (const float*)d_in[22];

    // ---- workspace layout (16B-aligned; ~50 MB) ----
    // persistent section
    float*    gacc   = (float*)d_ws;                   // 128,000 f
    float*    counts = gacc + 128000;                  // 512 f
    int*      cnt    = (int*)(counts + 512);           // 50,048 i
    short*    nodeb  = (short*)(cnt + 50048);          // 3,200,000
    short*    nnb    = nodeb + 3200000;                // 3,200,000
    short*    aggb   = nnb + 3200000;                  // 3,200,000
    short*    tabb   = aggb + 3200000;                 // 3 * 131,072
    unsigned* tabp   = (unsigned*)(tabb + 3 * 131072); // 3 * 131,072 u32
    short*    cw1t   = (short*)(tabp + 3 * 131072);    // 12,288
    short*    n2t    = cw1t + 12288;                   // 12,288
    short*    n3t    = n2t + 12288;                    // 12,288
    short*    d1t    = n3t + 12288;                    // 16,384
    short*    d2t    = d1t + 16384;                    // 65,536
    short*    act    = d2t + 65536;                    // 28,672
    short*    clswt  = act + 28672;                    // 524,288
    short*    gclsb  = clswt + 524288;                 // 128,000
    short*    embw0b = gclsb + 128000;                 // 6,400
    // tail section (dead after conv loop) — aliased by atomb in readout
    float*    node   = (float*)(embw0b + 6400);        // 3,200,000 f  (12.8 MB)
    unsigned* edata  = (unsigned*)(node + 3200000);    // 3,200,000 u32 (12.8 MB)
    short*    atomb  = (short*)node;                   // ALIAS: 25.6 MB over node+edata
    short*    resb   = atomb;                          // ALIAS: k_r2 reads atom rows first
    float*    out    = (float*)d_out;

    (void)hipMemsetAsync(gacc, 0, (128000 + 512) * sizeof(float) + 50048 * sizeof(int), stream);

    k_tw<<<2649, 256, 0, stream>>>(conv_w1, nl2_w, nl3_w, d1_w, d2_w, ac_w, cls_w, emb,
                                   cw1t, n2t, n3t, d1t, d2t, act, clswt, embw0b);
    k_table3<<<dim3(TAB / 4, 3), 256, 0, stream>>>(cf1_w, cf1_b, cf2_w, cf2_b, tabb);
    k_pack<<<dim3(512, 3), 256, 0, stream>>>(tabb, tabp);

    k_embed<<<(N_NODES * DIM + 255) / 256, 256, 0, stream>>>(node_types, emb, embw0b,
        node, nodeb, nnb, graph_ids, counts, edge_src, edge_dst, distance, cnt, edata);

    for (int i = 0; i < N_CONV; ++i){
        k_agg<<<(N_NODES + 3) / 4, 256, 0, stream>>>(edata, cnt, tabp + i * TAB * 64,
                                                     nnb, aggb);
        k_update<<<(N_NODES + 31) / 32, 256, 0, stream>>>(aggb,
            n2t + i * 4096, nl2_b + i * DIM, n3t + i * 4096, nl3_b + i * DIM,
            node, nodeb, (i < N_CONV - 1) ? (cw1t + (i + 1) * 4096) : (const short*)nullptr, nnb);
    }

    k_r1<<<(N_NODES + 31) / 32, 256, 0, stream>>>(nodeb, d1t, d1_b, atomb);
    k_r2<<<(N_NODES + 31) / 32, 256, 0, stream>>>(atomb, d2t, d2_b, graph_ids, gacc, resb);
    k_r3<<<(N_NODES + 63) / 64, 256, 0, stream>>>(resb, act, ac_b, out);
    k_embg<<<(N_GRAPHS * HID + 255) / 256, 256, 0, stream>>>(gacc, counts, gclsb);
    k_cls2<<<dim3((N_GRAPHS + 31) / 32, (CLS_DIM + 255) / 256), 256, 0, stream>>>(
        gclsb, clswt, cls_b, out + N_NODES * ACT_DIM);
}